// Round 1
// baseline (985.321 us; speedup 1.0000x reference)
//
#include <hip/hip_runtime.h>
#include <math.h>

#define NN 50000
#define FD 256
#define DE 128
#define RR 3
#define NP 4096
#define KN 32

// workspace layout (float offsets)
#define OFF_DPICK 0                 // [3][4096]
#define OFF_DNB   12288             // [3][4096][32]
#define OFF_DCD   405504            // [3][4096][32]
#define OFF_RHOM  798720            // [3]
#define OFF_RHOP  798724            // [3]
#define OFF_AGG   798976            // [4096][256]  (center + aggregated)

__device__ __forceinline__ int wave_red_int(int v) {
    #pragma unroll
    for (int o = 1; o < 64; o <<= 1) v += __shfl_xor(v, o);
    return v;
}
__device__ __forceinline__ double wave_red_dbl(double v) {
    #pragma unroll
    for (int o = 1; o < 64; o <<= 1) v += __shfl_xor(v, o);
    return v;
}

// ---------------------------------------------------------------------------
// Kernel 1: distance scores for picked / neigh / cand rows.
// One wave handles 128 consecutive rows (same segment & same r by divisibility).
// lane = s*16 + j  (s in [0,4) splits the 256-dim, j in [0,16) = hidden unit).
// W1 fragment lives in registers (64 VGPR), amortized over the 128 rows.
// ---------------------------------------------------------------------------
__global__ __launch_bounds__(256) void scores_kernel(
    const float* __restrict__ features,
    const float* __restrict__ W1, const float* __restrict__ b1,
    const float* __restrict__ W2, const float* __restrict__ b2,
    const int* __restrict__ picked, const int* __restrict__ neigh,
    const int* __restrict__ cand, float* ws)
{
    const int wid  = (blockIdx.x * 256 + threadIdx.x) >> 6;
    const int lane = threadIdx.x & 63;
    const int s = lane >> 4, j = lane & 15;
    const int base = wid * 128;

    int off, r;
    const int* idxsrc;
    float* dst;
    if (base < RR * NP) {                       // picked rows
        off = base; r = off >> 12; idxsrc = picked; dst = ws + OFF_DPICK;
    } else if (base < RR * NP + RR * NP * KN) { // neighbor rows
        off = base - RR * NP; r = off >> 17; idxsrc = neigh; dst = ws + OFF_DNB;
    } else {                                    // candidate rows
        off = base - RR * NP - RR * NP * KN; r = off >> 17; idxsrc = cand; dst = ws + OFF_DCD;
    }

    float w1f[64];
    const float* W1r = W1 + r * (FD * 16);
    #pragma unroll
    for (int tt = 0; tt < 64; ++tt) w1f[tt] = W1r[(s * 64 + tt) * 16 + j];
    const float b1v = b1[r * 16 + j];
    const float w2v = W2[(r * 16 + j) * 2 + 1];
    const float b2v = b2[r * 2 + 1];

    for (int i = 0; i < 128; ++i) {
        const int flat = off + i;
        const int node = idxsrc[flat];
        const float4* x4 = (const float4*)(features + (long)node * FD);
        float acc = 0.f;
        #pragma unroll
        for (int t4 = 0; t4 < 16; ++t4) {
            float4 xv = x4[s * 16 + t4];
            acc = fmaf(xv.x, w1f[4 * t4 + 0], acc);
            acc = fmaf(xv.y, w1f[4 * t4 + 1], acc);
            acc = fmaf(xv.z, w1f[4 * t4 + 2], acc);
            acc = fmaf(xv.w, w1f[4 * t4 + 3], acc);
        }
        acc += __shfl_xor(acc, 16);   // reduce over s
        acc += __shfl_xor(acc, 32);
        float h = fmaxf(acc + b1v, 0.f);
        float p = h * w2v;
        p += __shfl_xor(p, 1);        // reduce over j
        p += __shfl_xor(p, 2);
        p += __shfl_xor(p, 4);
        p += __shfl_xor(p, 8);
        if (lane == 0) {
            float logit = p + b2v;
            dst[flat] = 1.f / (1.f + expf(-logit));
        }
    }
}

// ---------------------------------------------------------------------------
// Kernel 2: rho selection. blocks 0..2 -> rho_minus[r]; blocks 3..5 -> rho_plus[r].
// ---------------------------------------------------------------------------
__global__ __launch_bounds__(1024) void rho_kernel(float* ws, const int* __restrict__ labels)
{
    __shared__ float cv[NP];
    __shared__ float cw[NP];
    __shared__ float cnd[2048];
    __shared__ float tval[32], bval[32];
    __shared__ float rv[16];
    __shared__ int   ri[16];
    __shared__ int   i1[16], i2[16], i3[16];
    __shared__ double dsh[16];
    __shared__ int    ish[16];
    __shared__ int    m_sh, npos_sh;
    __shared__ unsigned x_sh;
    __shared__ double dsum_sh;

    const int tid = threadIdx.x;
    const int lane = tid & 63, wv = tid >> 6;
    const float* dpick = ws + OFF_DPICK;

    if (blockIdx.x < 3) {
        // ---------------- rho_minus: exact mean of top-2048 ----------------
        const int r = blockIdx.x;
        const float* dnb = ws + OFF_DNB + r * (NP * KN);
        const float* dpr = dpick + r * NP;
        const int M = NP * KN, K = NP / 2;
        unsigned x = 0;
        for (int b = 28; b >= 0; b -= 2) {       // monotone-predicate bit search, 2 bits/pass
            const float f1 = __uint_as_float(x | (1u << b));
            const float f2 = __uint_as_float(x | (2u << b));
            const float f3 = __uint_as_float(x | (3u << b));
            int c1 = 0, c2 = 0, c3 = 0;
            for (int i = tid; i < M; i += 1024) {
                float v = fabsf(dpr[i >> 5] - dnb[i]);
                c1 += (v >= f1); c2 += (v >= f2); c3 += (v >= f3);
            }
            c1 = wave_red_int(c1); c2 = wave_red_int(c2); c3 = wave_red_int(c3);
            if (lane == 0) { i1[wv] = c1; i2[wv] = c2; i3[wv] = c3; }
            __syncthreads();
            if (tid == 0) {
                int s1 = 0, s2 = 0, s3 = 0;
                for (int w = 0; w < 16; ++w) { s1 += i1[w]; s2 += i2[w]; s3 += i3[w]; }
                unsigned nx = x;
                if (s3 >= K) nx = x | (3u << b);
                else if (s2 >= K) nx = x | (2u << b);
                else if (s1 >= K) nx = x | (1u << b);
                x_sh = nx;
            }
            __syncthreads();
            x = x_sh;
        }
        const float tv = __uint_as_float(x);     // exact K-th largest value
        double ps = 0.0; int pc = 0;
        for (int i = tid; i < M; i += 1024) {
            float v = fabsf(dpr[i >> 5] - dnb[i]);
            if (v > tv) { ps += (double)v; pc += 1; }
        }
        ps = wave_red_dbl(ps); pc = wave_red_int(pc);
        if (lane == 0) { dsh[wv] = ps; ish[wv] = pc; }
        __syncthreads();
        if (tid == 0) {
            double tot = 0; int cg = 0;
            for (int w = 0; w < 16; ++w) { tot += dsh[w]; cg += ish[w]; }
            tot += (double)(K - cg) * (double)tv;   // tie-aware fill
            ws[OFF_RHOM + r] = (float)(tot / (double)K);
        }
    } else {
        // ---------------- rho_plus: top-32 pairwise among minority ----------------
        const int r = blockIdx.x - 3;
        const float* dpr = dpick + r * NP;
        const int* lab = labels + r * NP;
        int np = 0;
        for (int i = tid; i < NP; i += 1024) np += lab[i];
        np = wave_red_int(np);
        if (lane == 0) ri[wv] = np;
        __syncthreads();
        if (tid == 0) {
            int sacc = 0;
            for (int w = 0; w < 16; ++w) sacc += ri[w];
            npos_sh = sacc; m_sh = 0;
        }
        __syncthreads();
        const int minority = (2 * npos_sh <= NP) ? 1 : 0;
        // compact minority values (ballot-based, 1 atomic per wave per iter)
        for (int i = tid; i < NP; i += 1024) {
            bool pred = (lab[i] == minority);
            unsigned long long bal = __ballot(pred);
            int wcnt = __popcll(bal);
            int woff = __popcll(bal & ((1ull << lane) - 1ull));
            int bb = 0;
            if (lane == 0) bb = atomicAdd(&m_sh, wcnt);
            bb = __shfl(bb, 0);
            if (pred) cv[bb + woff] = dpr[i];
        }
        __syncthreads();
        const int m = m_sh;

        if (m >= 64) {
            // top-32 (destructive argmax over working copy)
            for (int i = tid; i < NP; i += 1024) cw[i] = (i < m) ? cv[i] : -2.0f;
            __syncthreads();
            for (int rd = 0; rd < 32; ++rd) {
                float bv = -3.0f; int bp = 0;
                for (int i = tid; i < NP; i += 1024) { float xv = cw[i]; if (xv > bv) { bv = xv; bp = i; } }
                #pragma unroll
                for (int o = 1; o < 64; o <<= 1) {
                    float ov = __shfl_xor(bv, o); int op = __shfl_xor(bp, o);
                    if (ov > bv) { bv = ov; bp = op; }
                }
                if (lane == 0) { rv[wv] = bv; ri[wv] = bp; }
                __syncthreads();
                if (tid == 0) {
                    float best = -3.0f; int bpp = 0;
                    for (int w = 0; w < 16; ++w) if (rv[w] > best) { best = rv[w]; bpp = ri[w]; }
                    tval[rd] = best; cw[bpp] = -2.0f;
                }
                __syncthreads();
            }
            // bottom-32
            for (int i = tid; i < NP; i += 1024) cw[i] = (i < m) ? cv[i] : 3.0f;
            __syncthreads();
            for (int rd = 0; rd < 32; ++rd) {
                float bv = 3.0f; int bp = 0;
                for (int i = tid; i < NP; i += 1024) { float xv = cw[i]; if (xv < bv) { bv = xv; bp = i; } }
                #pragma unroll
                for (int o = 1; o < 64; o <<= 1) {
                    float ov = __shfl_xor(bv, o); int op = __shfl_xor(bp, o);
                    if (ov < bv) { bv = ov; bp = op; }
                }
                if (lane == 0) { rv[wv] = bv; ri[wv] = bp; }
                __syncthreads();
                if (tid == 0) {
                    float best = 3.0f; int bpp = 0;
                    for (int w = 0; w < 16; ++w) if (rv[w] < best) { best = rv[w]; bpp = ri[w]; }
                    bval[rd] = best; cw[bpp] = 3.0f;
                }
                __syncthreads();
            }
            cnd[tid] = tval[tid >> 5] - bval[tid & 31];   // 1024 candidates, all >= 0
            cnd[tid + 1024] = -1.0f;
        } else {
            cnd[tid] = -1.0f; cnd[tid + 1024] = -1.0f;
            __syncthreads();
            int idx = 0;
            for (int a = 0; a + 1 < m; ++a)
                for (int bq = a + 1; bq < m; ++bq) {
                    if ((idx & 1023) == tid) cnd[idx] = fabsf(cv[a] - cv[bq]);
                    ++idx;
                }
        }
        __syncthreads();
        if (tid == 0) dsum_sh = 0.0;
        __syncthreads();
        for (int rd = 0; rd < 32; ++rd) {       // top-32 of candidates, clamp>=0, mean/32
            float bv = -4.0f; int bp = 0;
            float xv = cnd[tid];        if (xv > bv) { bv = xv; bp = tid; }
            xv = cnd[tid + 1024];       if (xv > bv) { bv = xv; bp = tid + 1024; }
            #pragma unroll
            for (int o = 1; o < 64; o <<= 1) {
                float ov = __shfl_xor(bv, o); int op = __shfl_xor(bp, o);
                if (ov > bv) { bv = ov; bp = op; }
            }
            if (lane == 0) { rv[wv] = bv; ri[wv] = bp; }
            __syncthreads();
            if (tid == 0) {
                float best = -4.0f; int bpp = 0;
                for (int w = 0; w < 16; ++w) if (rv[w] > best) { best = rv[w]; bpp = ri[w]; }
                dsum_sh += (double)fmaxf(best, 0.0f);
                cnd[bpp] = -4.0f;
            }
            __syncthreads();
        }
        if (tid == 0) ws[OFF_RHOP + r] = (float)(dsum_sh / 32.0);
    }
}

// ---------------------------------------------------------------------------
// Kernel 3: aggregation. One wave per output row n (center + masked neighbor adds).
// ---------------------------------------------------------------------------
__global__ __launch_bounds__(256) void agg_kernel(
    const float* __restrict__ features,
    const int* __restrict__ picked, const int* __restrict__ neigh,
    const int* __restrict__ cndi, float* ws)
{
    const int n = __builtin_amdgcn_readfirstlane(blockIdx.x * 4 + (threadIdx.x >> 6));
    const int c4 = threadIdx.x & 63;
    const float* dpick = ws + OFF_DPICK;
    const float* dnb = ws + OFF_DNB;
    const float* dcd = ws + OFF_DCD;
    const float4* f4 = (const float4*)features;

    float4 acc = f4[(long)picked[n] * 64 + c4];   // center row (r = 0)
    for (int r = 0; r < RR; ++r) {
        const float dp = dpick[r * NP + n];
        const float rm = ws[OFF_RHOM + r];
        const float rp = ws[OFF_RHOP + r];
        const int base = (r * NP + n) * KN;
        #pragma unroll
        for (int k = 0; k < KN; ++k) {
            if (fabsf(dp - dnb[base + k]) < rm) {
                float4 v = f4[(long)neigh[base + k] * 64 + c4];
                acc.x += v.x; acc.y += v.y; acc.z += v.z; acc.w += v.w;
            }
        }
        #pragma unroll
        for (int k = 0; k < KN; ++k) {
            if (fabsf(dp - dcd[base + k]) < rp) {
                float4 v = f4[(long)cndi[base + k] * 64 + c4];
                acc.x += v.x; acc.y += v.y; acc.z += v.z; acc.w += v.w;
            }
        }
    }
    float4* agg4 = (float4*)(ws + OFF_AGG);
    agg4[(long)n * 64 + c4] = acc;
}

// ---------------------------------------------------------------------------
// Kernel 4: out = relu(W @ (center+agg)^T)   [128 x 4096]
// Tile: 32 n-cols x 32 dd-rows per block; sA stride-257 pad (2-way = free).
// ---------------------------------------------------------------------------
__global__ __launch_bounds__(256) void gemm_kernel(
    const float* __restrict__ weight, const float* ws, float* __restrict__ out)
{
    __shared__ __align__(16) float sW[32 * 256];
    __shared__ float sA[32 * 257];
    const int t = threadIdx.x;
    const int nt = blockIdx.x, dt = blockIdx.y;
    const float* agg = ws + OFF_AGG;

    const float4* w4 = (const float4*)(weight + dt * (32 * 256));
    float4* sW4 = (float4*)sW;
    #pragma unroll
    for (int i = 0; i < 8; ++i) sW4[i * 256 + t] = w4[i * 256 + t];

    const float4* a4 = (const float4*)agg + (long)nt * 2048;
    #pragma unroll
    for (int i = 0; i < 8; ++i) {
        int f4i = i * 256 + t;
        float4 v = a4[f4i];
        int row = f4i >> 6, c0 = (f4i & 63) << 2;
        sA[row * 257 + c0 + 0] = v.x;
        sA[row * 257 + c0 + 1] = v.y;
        sA[row * 257 + c0 + 2] = v.z;
        sA[row * 257 + c0 + 3] = v.w;
    }
    __syncthreads();

    const int n = t & 31, g = t >> 5;   // g in [0,8): 4 dd rows each
    const float* sAn = sA + n * 257;
    const float* sWg = sW + g * (4 * 256);
    float acc[4] = {0.f, 0.f, 0.f, 0.f};
    for (int c4 = 0; c4 < 64; ++c4) {
        float a0 = sAn[c4 * 4 + 0], a1 = sAn[c4 * 4 + 1];
        float a2 = sAn[c4 * 4 + 2], a3 = sAn[c4 * 4 + 3];
        #pragma unroll
        for (int i = 0; i < 4; ++i) {
            const float4 wvv = *(const float4*)(sWg + i * 256 + c4 * 4);
            acc[i] = fmaf(wvv.x, a0, acc[i]);
            acc[i] = fmaf(wvv.y, a1, acc[i]);
            acc[i] = fmaf(wvv.z, a2, acc[i]);
            acc[i] = fmaf(wvv.w, a3, acc[i]);
        }
    }
    float* outp = out + (long)(dt * 32 + g * 4) * 4096 + nt * 32 + n;
    #pragma unroll
    for (int i = 0; i < 4; ++i) outp[(long)i * 4096] = fmaxf(acc[i], 0.f);
}

// ---------------------------------------------------------------------------
extern "C" void kernel_launch(void* const* d_in, const int* in_sizes, int n_in,
                              void* d_out, int out_size, void* d_ws, size_t ws_size,
                              hipStream_t stream)
{
    const float* features = (const float*)d_in[0];
    const float* weight   = (const float*)d_in[1];
    const float* W1       = (const float*)d_in[2];
    const float* b1       = (const float*)d_in[3];
    const float* W2       = (const float*)d_in[4];
    const float* b2       = (const float*)d_in[5];
    const int*   picked   = (const int*)d_in[6];
    const int*   labels   = (const int*)d_in[7];
    const int*   neigh    = (const int*)d_in[8];
    const int*   cnd      = (const int*)d_in[9];
    float* out = (float*)d_out;
    float* ws  = (float*)d_ws;

    // 798720 rows / 128 rows-per-wave / 4 waves-per-block = 1560 blocks
    scores_kernel<<<1560, 256, 0, stream>>>(features, W1, b1, W2, b2, picked, neigh, cnd, ws);
    rho_kernel<<<6, 1024, 0, stream>>>(ws, labels);
    agg_kernel<<<1024, 256, 0, stream>>>(features, picked, neigh, cnd, ws);
    gemm_kernel<<<dim3(128, 4), 256, 0, stream>>>(weight, ws, out);
}

// Round 2
// 957.301 us; speedup vs baseline: 1.0293x; 1.0293x over previous
//
#include <hip/hip_runtime.h>
#include <math.h>

#define NN 50000
#define FD 256
#define DE 128
#define RR 3
#define NP 4096
#define KN 32

// workspace layout (float offsets)
#define OFF_DPICK 0                 // [3][4096]
#define OFF_DNB   12288             // [3][4096][32]
#define OFF_DCD   405504            // [3][4096][32]
#define OFF_RHOM  798720            // [3]
#define OFF_RHOP  798724            // [3]
#define OFF_AGG   798976            // [4096][256]  (center + aggregated)

__device__ __forceinline__ int wave_red_int(int v) {
    #pragma unroll
    for (int o = 1; o < 64; o <<= 1) v += __shfl_xor(v, o);
    return v;
}
__device__ __forceinline__ double wave_red_dbl(double v) {
    #pragma unroll
    for (int o = 1; o < 64; o <<= 1) v += __shfl_xor(v, o);
    return v;
}

// ---------------------------------------------------------------------------
// Kernel 1: distance scores. One wave = 32 rows. Indices preloaded (1 coalesced
// load + shfl), rows pipelined (unroll 2), one coalesced store per wave.
// lane = s*16 + j  (s in [0,4) splits the 256-dim, j in [0,16) = hidden unit).
// ---------------------------------------------------------------------------
__global__ __launch_bounds__(256, 4) void scores_kernel(
    const float* __restrict__ features,
    const float* __restrict__ W1, const float* __restrict__ b1,
    const float* __restrict__ W2, const float* __restrict__ b2,
    const int* __restrict__ picked, const int* __restrict__ neigh,
    const int* __restrict__ cand, float* ws)
{
    const int wid  = (blockIdx.x * 256 + threadIdx.x) >> 6;
    const int lane = threadIdx.x & 63;
    const int s = lane >> 4, j = lane & 15;
    const int base = wid * 32;

    int off, r;
    const int* idxsrc;
    float* dst;
    if (base < RR * NP) {                       // picked rows
        off = base; r = off >> 12; idxsrc = picked; dst = ws + OFF_DPICK;
    } else if (base < RR * NP + RR * NP * KN) { // neighbor rows
        off = base - RR * NP; r = off >> 17; idxsrc = neigh; dst = ws + OFF_DNB;
    } else {                                    // candidate rows
        off = base - RR * NP - RR * NP * KN; r = off >> 17; idxsrc = cand; dst = ws + OFF_DCD;
    }

    const int myidx = idxsrc[off + (lane & 31)];   // all 32 row indices, in-register

    float w1f[64];
    const float* W1r = W1 + r * (FD * 16);
    #pragma unroll
    for (int tt = 0; tt < 64; ++tt) w1f[tt] = W1r[(s * 64 + tt) * 16 + j];
    const float b1v = b1[r * 16 + j];
    const float w2v = W2[(r * 16 + j) * 2 + 1];
    const float b2v = b2[r * 2 + 1];

    float res = 0.f;
    #pragma unroll 2
    for (int i = 0; i < 32; ++i) {
        const int node = __shfl(myidx, i);
        const float4* x4 = (const float4*)(features + (long)node * FD);
        float acc = 0.f;
        #pragma unroll
        for (int t4 = 0; t4 < 16; ++t4) {
            float4 xv = x4[s * 16 + t4];
            acc = fmaf(xv.x, w1f[4 * t4 + 0], acc);
            acc = fmaf(xv.y, w1f[4 * t4 + 1], acc);
            acc = fmaf(xv.z, w1f[4 * t4 + 2], acc);
            acc = fmaf(xv.w, w1f[4 * t4 + 3], acc);
        }
        acc += __shfl_xor(acc, 16);   // reduce over s
        acc += __shfl_xor(acc, 32);
        float h = fmaxf(acc + b1v, 0.f);
        float p = h * w2v;
        p += __shfl_xor(p, 1);        // reduce over j
        p += __shfl_xor(p, 2);
        p += __shfl_xor(p, 4);
        p += __shfl_xor(p, 8);
        if (lane == i) res = p;       // full sum replicated in all 64 lanes
    }
    if (lane < 32) dst[off + lane] = 1.f / (1.f + expf(-(res + b2v)));
}

// ---------------------------------------------------------------------------
// Kernel 2: rho selection. blocks 0..2 -> rho_minus[r]; blocks 3..5 -> rho_plus[r].
// ---------------------------------------------------------------------------
__global__ __launch_bounds__(1024) void rho_kernel(float* ws, const int* __restrict__ labels)
{
    __shared__ float cv[NP];
    __shared__ float cw[NP];
    __shared__ float cnd[2048];
    __shared__ float tval[32], bval[32];
    __shared__ float rv[16];
    __shared__ int   ri[16];
    __shared__ int   cnt_sh[7][16];
    __shared__ double dsh[16];
    __shared__ int    ish[16];
    __shared__ int    m_sh, npos_sh;
    __shared__ unsigned x_sh;
    __shared__ double dsum_sh;

    const int tid = threadIdx.x;
    const int lane = tid & 63, wv = tid >> 6;
    const float* dpick = ws + OFF_DPICK;

    if (blockIdx.x < 3) {
        // ---------------- rho_minus: exact mean of top-2048 ----------------
        const int r = blockIdx.x;
        const float* __restrict__ dnb = ws + OFF_DNB + r * (NP * KN);
        const float* __restrict__ dpr = dpick + r * NP;
        const int M = NP * KN, K = NP / 2;
        unsigned x = 0;
        for (int b = 27; b >= 0; b -= 3) {       // 3 bits/pass, 10 passes
            int cnt[7];
            #pragma unroll
            for (int q = 0; q < 7; ++q) cnt[q] = 0;
            for (int i = tid; i < M; i += 1024) {
                unsigned vb = __float_as_uint(fabsf(dpr[i >> 5] - dnb[i]));
                #pragma unroll
                for (int q = 0; q < 7; ++q) cnt[q] += (vb >= (x | ((unsigned)(q + 1) << b)));
            }
            #pragma unroll
            for (int q = 0; q < 7; ++q) cnt[q] = wave_red_int(cnt[q]);
            if (lane == 0) {
                #pragma unroll
                for (int q = 0; q < 7; ++q) cnt_sh[q][wv] = cnt[q];
            }
            __syncthreads();
            if (tid == 0) {
                unsigned nx = x;
                for (int q = 6; q >= 0; --q) {
                    int tot = 0;
                    for (int w = 0; w < 16; ++w) tot += cnt_sh[q][w];
                    if (tot >= K) { nx = x | ((unsigned)(q + 1) << b); break; }
                }
                x_sh = nx;
            }
            __syncthreads();
            x = x_sh;
        }
        // x = exact K-th largest bit pattern
        double ps = 0.0; int pc = 0;
        for (int i = tid; i < M; i += 1024) {
            float v = fabsf(dpr[i >> 5] - dnb[i]);
            if (__float_as_uint(v) > x) { ps += (double)v; pc += 1; }
        }
        ps = wave_red_dbl(ps); pc = wave_red_int(pc);
        if (lane == 0) { dsh[wv] = ps; ish[wv] = pc; }
        __syncthreads();
        if (tid == 0) {
            double tot = 0; int cg = 0;
            for (int w = 0; w < 16; ++w) { tot += dsh[w]; cg += ish[w]; }
            tot += (double)(K - cg) * (double)__uint_as_float(x);   // tie-aware fill
            ws[OFF_RHOM + r] = (float)(tot / (double)K);
        }
    } else {
        // ---------------- rho_plus: top-32 pairwise among minority ----------------
        const int r = blockIdx.x - 3;
        const float* dpr = dpick + r * NP;
        const int* lab = labels + r * NP;
        int np = 0;
        for (int i = tid; i < NP; i += 1024) np += lab[i];
        np = wave_red_int(np);
        if (lane == 0) ri[wv] = np;
        __syncthreads();
        if (tid == 0) {
            int sacc = 0;
            for (int w = 0; w < 16; ++w) sacc += ri[w];
            npos_sh = sacc; m_sh = 0;
        }
        __syncthreads();
        const int minority = (2 * npos_sh <= NP) ? 1 : 0;
        for (int i = tid; i < NP; i += 1024) {
            bool pred = (lab[i] == minority);
            unsigned long long bal = __ballot(pred);
            int wcnt = __popcll(bal);
            int woff = __popcll(bal & ((1ull << lane) - 1ull));
            int bb = 0;
            if (lane == 0) bb = atomicAdd(&m_sh, wcnt);
            bb = __shfl(bb, 0);
            if (pred) cv[bb + woff] = dpr[i];
        }
        __syncthreads();
        const int m = m_sh;

        if (m >= 64) {
            for (int i = tid; i < NP; i += 1024) cw[i] = (i < m) ? cv[i] : -2.0f;
            __syncthreads();
            for (int rd = 0; rd < 32; ++rd) {
                float bv = -3.0f; int bp = 0;
                for (int i = tid; i < NP; i += 1024) { float xv = cw[i]; if (xv > bv) { bv = xv; bp = i; } }
                #pragma unroll
                for (int o = 1; o < 64; o <<= 1) {
                    float ov = __shfl_xor(bv, o); int op = __shfl_xor(bp, o);
                    if (ov > bv) { bv = ov; bp = op; }
                }
                if (lane == 0) { rv[wv] = bv; ri[wv] = bp; }
                __syncthreads();
                if (tid == 0) {
                    float best = -3.0f; int bpp = 0;
                    for (int w = 0; w < 16; ++w) if (rv[w] > best) { best = rv[w]; bpp = ri[w]; }
                    tval[rd] = best; cw[bpp] = -2.0f;
                }
                __syncthreads();
            }
            for (int i = tid; i < NP; i += 1024) cw[i] = (i < m) ? cv[i] : 3.0f;
            __syncthreads();
            for (int rd = 0; rd < 32; ++rd) {
                float bv = 3.0f; int bp = 0;
                for (int i = tid; i < NP; i += 1024) { float xv = cw[i]; if (xv < bv) { bv = xv; bp = i; } }
                #pragma unroll
                for (int o = 1; o < 64; o <<= 1) {
                    float ov = __shfl_xor(bv, o); int op = __shfl_xor(bp, o);
                    if (ov < bv) { bv = ov; bp = op; }
                }
                if (lane == 0) { rv[wv] = bv; ri[wv] = bp; }
                __syncthreads();
                if (tid == 0) {
                    float best = 3.0f; int bpp = 0;
                    for (int w = 0; w < 16; ++w) if (rv[w] < best) { best = rv[w]; bpp = ri[w]; }
                    bval[rd] = best; cw[bpp] = 3.0f;
                }
                __syncthreads();
            }
            cnd[tid] = tval[tid >> 5] - bval[tid & 31];
            cnd[tid + 1024] = -1.0f;
        } else {
            cnd[tid] = -1.0f; cnd[tid + 1024] = -1.0f;
            __syncthreads();
            int idx = 0;
            for (int a = 0; a + 1 < m; ++a)
                for (int bq = a + 1; bq < m; ++bq) {
                    if ((idx & 1023) == tid) cnd[idx] = fabsf(cv[a] - cv[bq]);
                    ++idx;
                }
        }
        __syncthreads();
        if (tid == 0) dsum_sh = 0.0;
        __syncthreads();
        for (int rd = 0; rd < 32; ++rd) {
            float bv = -4.0f; int bp = 0;
            float xv = cnd[tid];        if (xv > bv) { bv = xv; bp = tid; }
            xv = cnd[tid + 1024];       if (xv > bv) { bv = xv; bp = tid + 1024; }
            #pragma unroll
            for (int o = 1; o < 64; o <<= 1) {
                float ov = __shfl_xor(bv, o); int op = __shfl_xor(bp, o);
                if (ov > bv) { bv = ov; bp = op; }
            }
            if (lane == 0) { rv[wv] = bv; ri[wv] = bp; }
            __syncthreads();
            if (tid == 0) {
                float best = -4.0f; int bpp = 0;
                for (int w = 0; w < 16; ++w) if (rv[w] > best) { best = rv[w]; bpp = ri[w]; }
                dsum_sh += (double)fmaxf(best, 0.0f);
                cnd[bpp] = -4.0f;
            }
            __syncthreads();
        }
        if (tid == 0) ws[OFF_RHOP + r] = (float)(dsum_sh / 32.0);
    }
}

// ---------------------------------------------------------------------------
// Kernel 3: aggregation. One wave per output row n. Indices & scores preloaded
// (lane-parallel), mask via ballot, rows loaded unconditionally in batches of 8
// (mask applied as 0/1 multiplier) for deep MLP.
// ---------------------------------------------------------------------------
__global__ __launch_bounds__(256) void agg_kernel(
    const float* __restrict__ features,
    const int* __restrict__ picked, const int* __restrict__ neigh,
    const int* __restrict__ cndi, float* ws)
{
    const int n = __builtin_amdgcn_readfirstlane(blockIdx.x * 4 + (threadIdx.x >> 6));
    const int lane = threadIdx.x & 63;
    const int c4 = lane;
    const int k32 = lane & 31;
    const float4* f4 = (const float4*)features;

    float4 acc = f4[(long)picked[n] * 64 + c4];   // center row
    #pragma unroll
    for (int r = 0; r < RR; ++r) {
        const float dp = ws[OFF_DPICK + r * NP + n];
        const int base = (r * NP + n) * KN;
        #pragma unroll
        for (int which = 0; which < 2; ++which) {
            const float rho = ws[(which == 0 ? OFF_RHOM : OFF_RHOP) + r];
            const int* __restrict__ isrc = (which == 0) ? neigh : cndi;
            const float* dsrc = ws + (which == 0 ? OFF_DNB : OFF_DCD);
            const int   id = isrc[base + k32];
            const float dv = dsrc[base + k32];
            unsigned long long bal = __ballot(fabsf(dp - dv) < rho);
            const unsigned msk = (unsigned)bal;   // lanes 32-63 mirror 0-31
            #pragma unroll
            for (int c = 0; c < 4; ++c) {
                float4 v[8];
                #pragma unroll
                for (int q = 0; q < 8; ++q) {
                    int node = __shfl(id, c * 8 + q);
                    v[q] = f4[(long)node * 64 + c4];
                }
                #pragma unroll
                for (int q = 0; q < 8; ++q) {
                    float mfl = ((msk >> (c * 8 + q)) & 1) ? 1.f : 0.f;
                    acc.x = fmaf(v[q].x, mfl, acc.x);
                    acc.y = fmaf(v[q].y, mfl, acc.y);
                    acc.z = fmaf(v[q].z, mfl, acc.z);
                    acc.w = fmaf(v[q].w, mfl, acc.w);
                }
            }
        }
    }
    float4* agg4 = (float4*)(ws + OFF_AGG);
    agg4[(long)n * 64 + c4] = acc;
}

// ---------------------------------------------------------------------------
// Kernel 4: out = relu(W @ (center+agg)^T)   [128 x 4096]
// ---------------------------------------------------------------------------
__global__ __launch_bounds__(256) void gemm_kernel(
    const float* __restrict__ weight, const float* ws, float* __restrict__ out)
{
    __shared__ __align__(16) float sW[32 * 256];
    __shared__ float sA[32 * 257];
    const int t = threadIdx.x;
    const int nt = blockIdx.x, dt = blockIdx.y;
    const float* agg = ws + OFF_AGG;

    const float4* w4 = (const float4*)(weight + dt * (32 * 256));
    float4* sW4 = (float4*)sW;
    #pragma unroll
    for (int i = 0; i < 8; ++i) sW4[i * 256 + t] = w4[i * 256 + t];

    const float4* a4 = (const float4*)agg + (long)nt * 2048;
    #pragma unroll
    for (int i = 0; i < 8; ++i) {
        int f4i = i * 256 + t;
        float4 v = a4[f4i];
        int row = f4i >> 6, c0 = (f4i & 63) << 2;
        sA[row * 257 + c0 + 0] = v.x;
        sA[row * 257 + c0 + 1] = v.y;
        sA[row * 257 + c0 + 2] = v.z;
        sA[row * 257 + c0 + 3] = v.w;
    }
    __syncthreads();

    const int n = t & 31, g = t >> 5;
    const float* sAn = sA + n * 257;
    const float* sWg = sW + g * (4 * 256);
    float acc[4] = {0.f, 0.f, 0.f, 0.f};
    for (int c4 = 0; c4 < 64; ++c4) {
        float a0 = sAn[c4 * 4 + 0], a1 = sAn[c4 * 4 + 1];
        float a2 = sAn[c4 * 4 + 2], a3 = sAn[c4 * 4 + 3];
        #pragma unroll
        for (int i = 0; i < 4; ++i) {
            const float4 wvv = *(const float4*)(sWg + i * 256 + c4 * 4);
            acc[i] = fmaf(wvv.x, a0, acc[i]);
            acc[i] = fmaf(wvv.y, a1, acc[i]);
            acc[i] = fmaf(wvv.z, a2, acc[i]);
            acc[i] = fmaf(wvv.w, a3, acc[i]);
        }
    }
    float* outp = out + (long)(dt * 32 + g * 4) * 4096 + nt * 32 + n;
    #pragma unroll
    for (int i = 0; i < 4; ++i) outp[(long)i * 4096] = fmaxf(acc[i], 0.f);
}

// ---------------------------------------------------------------------------
extern "C" void kernel_launch(void* const* d_in, const int* in_sizes, int n_in,
                              void* d_out, int out_size, void* d_ws, size_t ws_size,
                              hipStream_t stream)
{
    const float* features = (const float*)d_in[0];
    const float* weight   = (const float*)d_in[1];
    const float* W1       = (const float*)d_in[2];
    const float* b1       = (const float*)d_in[3];
    const float* W2       = (const float*)d_in[4];
    const float* b2       = (const float*)d_in[5];
    const int*   picked   = (const int*)d_in[6];
    const int*   labels   = (const int*)d_in[7];
    const int*   neigh    = (const int*)d_in[8];
    const int*   cnd      = (const int*)d_in[9];
    float* out = (float*)d_out;
    float* ws  = (float*)d_ws;

    // 798720 rows / 32 rows-per-wave / 4 waves-per-block = 6240 blocks
    scores_kernel<<<6240, 256, 0, stream>>>(features, W1, b1, W2, b2, picked, neigh, cnd, ws);
    rho_kernel<<<6, 1024, 0, stream>>>(ws, labels);
    agg_kernel<<<1024, 256, 0, stream>>>(features, picked, neigh, cnd, ws);
    gemm_kernel<<<dim3(128, 4), 256, 0, stream>>>(weight, ws, out);
}

// Round 3
// 561.506 us; speedup vs baseline: 1.7548x; 1.7049x over previous
//
#include <hip/hip_runtime.h>
#include <math.h>

#define NN 50000
#define FD 256
#define DE 128
#define RR 3
#define NP 4096
#define KN 32

// workspace layout (float offsets)
#define OFF_DPICK 0                 // [3][4096]   raw d for picked nodes
#define OFF_DNB   12288             // [3][4096][32]  |d_pick - d_neigh|  (pre-abs'd diffs)
#define OFF_DCD   405504            // [3][4096][32]  |d_pick - d_cand|
#define OFF_RHOM  798720            // [3]
#define OFF_RHOP  798724            // [3]
#define OFF_DALL  798976            // [3][50000]  (aliases AGG; dead before agg writes)
#define OFF_AGG   798976            // [4096][256]

__device__ __forceinline__ int wave_red_int(int v) {
    #pragma unroll
    for (int o = 1; o < 64; o <<= 1) v += __shfl_xor(v, o);
    return v;
}
__device__ __forceinline__ double wave_red_dbl(double v) {
    #pragma unroll
    for (int o = 1; o < 64; o <<= 1) v += __shfl_xor(v, o);
    return v;
}

// exact K-th largest bit pattern of non-negative floats (<2.0) in LDS array arr[0..L)
// 3 bits per pass, 10 passes. All 1024 threads must call uniformly.
__device__ unsigned kth_bits(const float* arr, int L, int K,
                             int (*cnt_sh)[16], unsigned* x_sh_p) {
    const int tid = threadIdx.x, lane = tid & 63, wv = tid >> 6;
    unsigned x = 0;
    for (int b = 27; b >= 0; b -= 3) {
        int cnt[7];
        #pragma unroll
        for (int q = 0; q < 7; ++q) cnt[q] = 0;
        for (int i = tid; i < L; i += 1024) {
            unsigned vb = __float_as_uint(arr[i]);
            #pragma unroll
            for (int q = 0; q < 7; ++q) cnt[q] += (vb >= (x | ((unsigned)(q + 1) << b)));
        }
        #pragma unroll
        for (int q = 0; q < 7; ++q) cnt[q] = wave_red_int(cnt[q]);
        if (lane == 0) {
            #pragma unroll
            for (int q = 0; q < 7; ++q) cnt_sh[q][wv] = cnt[q];
        }
        __syncthreads();
        if (tid == 0) {
            unsigned nx = x;
            for (int q = 6; q >= 0; --q) {
                int tot = 0;
                for (int w = 0; w < 16; ++w) tot += cnt_sh[q][w];
                if (tot >= K) { nx = x | ((unsigned)(q + 1) << b); break; }
            }
            *x_sh_p = nx;
        }
        __syncthreads();
        x = *x_sh_p;
        __syncthreads();
    }
    return x;
}

// ---------------------------------------------------------------------------
// Kernel 1: d_all[r][node] for ALL nodes (dedup: 150K MLP evals, not 798K).
// Wave = 32 contiguous nodes; lane=(s,j): s quarters the 256-dim, j = hidden unit.
// ---------------------------------------------------------------------------
__global__ __launch_bounds__(256, 4) void dall_kernel(
    const float* __restrict__ features,
    const float* __restrict__ W1, const float* __restrict__ b1,
    const float* __restrict__ W2, const float* __restrict__ b2,
    float* ws)
{
    const int r = blockIdx.y;
    const int wid = blockIdx.x * 4 + (threadIdx.x >> 6);
    const int lane = threadIdx.x & 63;
    const int s = lane >> 4, j = lane & 15;
    const int base = wid * 32;
    if (base >= NN) return;

    float w1f[64];
    const float* W1r = W1 + r * (FD * 16);
    #pragma unroll
    for (int tt = 0; tt < 64; ++tt) w1f[tt] = W1r[(s * 64 + tt) * 16 + j];
    const float b1v = b1[r * 16 + j];
    const float w2v = W2[(r * 16 + j) * 2 + 1];
    const float b2v = b2[r * 2 + 1];

    float res = 0.f;
    #pragma unroll 2
    for (int i = 0; i < 32; ++i) {
        const int node = min(base + i, NN - 1);
        const float4* x4 = (const float4*)(features + (long)node * FD);
        float acc = 0.f;
        #pragma unroll
        for (int t4 = 0; t4 < 16; ++t4) {
            float4 xv = x4[s * 16 + t4];
            acc = fmaf(xv.x, w1f[4 * t4 + 0], acc);
            acc = fmaf(xv.y, w1f[4 * t4 + 1], acc);
            acc = fmaf(xv.z, w1f[4 * t4 + 2], acc);
            acc = fmaf(xv.w, w1f[4 * t4 + 3], acc);
        }
        acc += __shfl_xor(acc, 16);   // reduce over s
        acc += __shfl_xor(acc, 32);
        float h = fmaxf(acc + b1v, 0.f);
        float p = h * w2v;
        p += __shfl_xor(p, 1);        // reduce over j
        p += __shfl_xor(p, 2);
        p += __shfl_xor(p, 4);
        p += __shfl_xor(p, 8);
        if (lane == i) res = p;
    }
    const int node = base + lane;
    if (lane < 32 && node < NN)
        ws[OFF_DALL + r * NN + node] = 1.f / (1.f + expf(-(res + b2v)));
}

// ---------------------------------------------------------------------------
// Kernel 2: gather d_pick (raw) and |d_pick - d_nb| / |d_pick - d_cd| diffs.
// ---------------------------------------------------------------------------
__global__ __launch_bounds__(256) void gather_kernel(
    const int* __restrict__ picked, const int* __restrict__ neigh,
    const int* __restrict__ cand, float* ws)
{
    const int t = blockIdx.x * 256 + threadIdx.x;
    const float* dall = ws + OFF_DALL;
    if (t < RR * NP) {
        const int r = t >> 12;
        ws[OFF_DPICK + t] = dall[r * NN + picked[t]];
    } else if (t < RR * NP + RR * NP * KN) {
        const int off = t - RR * NP;
        const int r = off >> 17;
        const int n = (off >> 5) & (NP - 1);
        const float dp = dall[r * NN + picked[r * NP + n]];
        ws[OFF_DNB + off] = fabsf(dp - dall[r * NN + neigh[off]]);
    } else {
        const int off = t - RR * NP - RR * NP * KN;
        const int r = off >> 17;
        const int n = (off >> 5) & (NP - 1);
        const float dp = dall[r * NN + picked[r * NP + n]];
        ws[OFF_DCD + off] = fabsf(dp - dall[r * NN + cand[off]]);
    }
}

// ---------------------------------------------------------------------------
// Kernel 3: rho selection. blocks 0..2 rho_minus[r]; blocks 3..5 rho_plus[r].
// ---------------------------------------------------------------------------
__global__ __launch_bounds__(1024) void rho_kernel(float* ws, const int* __restrict__ labels)
{
    __shared__ float cv[2048];        // minority values (m <= 2048)
    __shared__ float cnd[2048];       // candidate differences
    __shared__ float tvb[64];         // [0..31] top multiset, [32..63] bottom multiset
    __shared__ int   cnt_sh[7][16];
    __shared__ int   ired[16];
    __shared__ double dred[16];
    __shared__ int   m_sh, npos_sh, cnt2_sh;
    __shared__ unsigned x_sh;

    const int tid = threadIdx.x;
    const int lane = tid & 63, wv = tid >> 6;

    if (blockIdx.x < 3) {
        // ---------------- rho_minus: exact mean of top-2048 diffs ----------------
        const int r = blockIdx.x;
        const float* __restrict__ dnb = ws + OFF_DNB + r * (NP * KN);
        const int M = NP * KN, K = NP / 2;
        unsigned x = 0;
        for (int b = 27; b >= 0; b -= 3) {
            int cnt[7];
            #pragma unroll
            for (int q = 0; q < 7; ++q) cnt[q] = 0;
            for (int i = tid; i < M; i += 1024) {
                unsigned vb = __float_as_uint(dnb[i]);
                #pragma unroll
                for (int q = 0; q < 7; ++q) cnt[q] += (vb >= (x | ((unsigned)(q + 1) << b)));
            }
            #pragma unroll
            for (int q = 0; q < 7; ++q) cnt[q] = wave_red_int(cnt[q]);
            if (lane == 0) {
                #pragma unroll
                for (int q = 0; q < 7; ++q) cnt_sh[q][wv] = cnt[q];
            }
            __syncthreads();
            if (tid == 0) {
                unsigned nx = x;
                for (int q = 6; q >= 0; --q) {
                    int tot = 0;
                    for (int w = 0; w < 16; ++w) tot += cnt_sh[q][w];
                    if (tot >= K) { nx = x | ((unsigned)(q + 1) << b); break; }
                }
                x_sh = nx;
            }
            __syncthreads();
            x = x_sh;
            __syncthreads();
        }
        double ps = 0.0; int pc = 0;
        for (int i = tid; i < M; i += 1024) {
            float v = dnb[i];
            if (__float_as_uint(v) > x) { ps += (double)v; pc += 1; }
        }
        ps = wave_red_dbl(ps); pc = wave_red_int(pc);
        if (lane == 0) { dred[wv] = ps; ired[wv] = pc; }
        __syncthreads();
        if (tid == 0) {
            double tot = 0; int cg = 0;
            for (int w = 0; w < 16; ++w) { tot += dred[w]; cg += ired[w]; }
            tot += (double)(K - cg) * (double)__uint_as_float(x);
            ws[OFF_RHOM + r] = (float)(tot / (double)K);
        }
    } else {
        // ---------------- rho_plus: top-32 pairwise among minority ----------------
        const int r = blockIdx.x - 3;
        const float* dpr = ws + OFF_DPICK + r * NP;
        const int* lab = labels + r * NP;
        int np = 0;
        for (int i = tid; i < NP; i += 1024) np += lab[i];
        np = wave_red_int(np);
        if (lane == 0) ired[wv] = np;
        __syncthreads();
        if (tid == 0) {
            int sacc = 0;
            for (int w = 0; w < 16; ++w) sacc += ired[w];
            npos_sh = sacc; m_sh = 0;
        }
        __syncthreads();
        const int minority = (2 * npos_sh <= NP) ? 1 : 0;
        for (int i = tid; i < NP; i += 1024) {
            bool pred = (lab[i] == minority);
            unsigned long long bal = __ballot(pred);
            int wcnt = __popcll(bal);
            int woff = __popcll(bal & ((1ull << lane) - 1ull));
            int bb = 0;
            if (lane == 0 && wcnt) bb = atomicAdd(&m_sh, wcnt);
            bb = __shfl(bb, 0);
            if (pred) cv[bb + woff] = dpr[i];
        }
        __syncthreads();
        const int m = m_sh;

        if (m >= 64) {
            // top-32 multiset via bit-search threshold
            const unsigned thi = kth_bits(cv, m, 32, cnt_sh, &x_sh);
            if (tid == 0) cnt2_sh = 0;
            __syncthreads();
            for (int i = tid; i < m; i += 1024) {
                bool pred = __float_as_uint(cv[i]) > thi;
                unsigned long long bal = __ballot(pred);
                int wcnt = __popcll(bal);
                int woff = __popcll(bal & ((1ull << lane) - 1ull));
                int bb = 0;
                if (lane == 0 && wcnt) bb = atomicAdd(&cnt2_sh, wcnt);
                bb = __shfl(bb, 0);
                if (pred) tvb[bb + woff] = cv[i];
            }
            __syncthreads();
            if (tid < 32 && tid >= cnt2_sh) tvb[tid] = __uint_as_float(thi);
            __syncthreads();
            // bottom-32 multiset = top with K = m-31
            const unsigned tlo = kth_bits(cv, m, m - 31, cnt_sh, &x_sh);
            if (tid == 0) cnt2_sh = 0;
            __syncthreads();
            for (int i = tid; i < m; i += 1024) {
                bool pred = __float_as_uint(cv[i]) < tlo;
                unsigned long long bal = __ballot(pred);
                int wcnt = __popcll(bal);
                int woff = __popcll(bal & ((1ull << lane) - 1ull));
                int bb = 0;
                if (lane == 0 && wcnt) bb = atomicAdd(&cnt2_sh, wcnt);
                bb = __shfl(bb, 0);
                if (pred) tvb[32 + bb + woff] = cv[i];
            }
            __syncthreads();
            if (tid < 32 && tid >= cnt2_sh) tvb[32 + tid] = __uint_as_float(tlo);
            __syncthreads();
            cnd[tid] = tvb[tid >> 5] - tvb[32 + (tid & 31)];  // all >= 0
            cnd[tid + 1024] = 0.0f;
        } else {
            cnd[tid] = 0.0f; cnd[tid + 1024] = 0.0f;
            __syncthreads();
            int idx = 0;
            for (int a = 0; a + 1 < m; ++a)
                for (int bq = a + 1; bq < m; ++bq) {
                    if ((idx & 1023) == tid) cnd[idx] = fabsf(cv[a] - cv[bq]);
                    ++idx;
                }
        }
        __syncthreads();
        const unsigned tc = kth_bits(cnd, 2048, 32, cnt_sh, &x_sh);
        double ps = 0.0; int pc = 0;
        {
            float v = cnd[tid];
            if (__float_as_uint(v) > tc) { ps += (double)v; pc += 1; }
            v = cnd[tid + 1024];
            if (__float_as_uint(v) > tc) { ps += (double)v; pc += 1; }
        }
        ps = wave_red_dbl(ps); pc = wave_red_int(pc);
        if (lane == 0) { dred[wv] = ps; ired[wv] = pc; }
        __syncthreads();
        if (tid == 0) {
            double tot = 0; int cg = 0;
            for (int w = 0; w < 16; ++w) { tot += dred[w]; cg += ired[w]; }
            tot += (double)(32 - cg) * (double)__uint_as_float(tc);
            ws[OFF_RHOP + r] = (float)(tot / 32.0);
        }
    }
}

// ---------------------------------------------------------------------------
// Kernel 4: aggregation. 2 waves per n: half0 = center + neigh rows (rho_minus),
// half1 = cand rows (rho_plus). LDS combine. 8192 waves total.
// ---------------------------------------------------------------------------
__global__ __launch_bounds__(256) void agg_kernel(
    const float* __restrict__ features,
    const int* __restrict__ picked, const int* __restrict__ neigh,
    const int* __restrict__ cndi, float* ws)
{
    __shared__ float4 sacc[2][64];
    const int wvid = threadIdx.x >> 6;
    const int half = wvid & 1;
    const int pair = wvid >> 1;
    const int n = __builtin_amdgcn_readfirstlane(blockIdx.x * 2 + pair);
    const int lane = threadIdx.x & 63;
    const float4* f4 = (const float4*)features;

    float4 acc = {0.f, 0.f, 0.f, 0.f};
    if (half == 0) acc = f4[(long)picked[n] * 64 + lane];
    const int* __restrict__ isrc = half ? cndi : neigh;
    const float* dsrc = ws + (half ? OFF_DCD : OFF_DNB);
    #pragma unroll
    for (int r = 0; r < RR; ++r) {
        const float rho = ws[(half ? OFF_RHOP : OFF_RHOM) + r];
        const int base = (r * NP + n) * KN;
        const int   id = isrc[base + (lane & 31)];
        const float dv = dsrc[base + (lane & 31)];
        unsigned long long bal = __ballot(dv < rho);
        const unsigned msk = (unsigned)bal;   // lanes 32-63 mirror 0-31
        #pragma unroll
        for (int c = 0; c < 4; ++c) {
            float4 v[8];
            #pragma unroll
            for (int q = 0; q < 8; ++q) {
                int node = __shfl(id, c * 8 + q);
                v[q] = f4[(long)node * 64 + lane];
            }
            #pragma unroll
            for (int q = 0; q < 8; ++q) {
                float mfl = ((msk >> (c * 8 + q)) & 1) ? 1.f : 0.f;
                acc.x = fmaf(v[q].x, mfl, acc.x);
                acc.y = fmaf(v[q].y, mfl, acc.y);
                acc.z = fmaf(v[q].z, mfl, acc.z);
                acc.w = fmaf(v[q].w, mfl, acc.w);
            }
        }
    }
    if (half == 1) sacc[pair][lane] = acc;
    __syncthreads();
    if (half == 0) {
        float4 o = sacc[pair][lane];
        acc.x += o.x; acc.y += o.y; acc.z += o.z; acc.w += o.w;
        float4* agg4 = (float4*)(ws + OFF_AGG);
        agg4[(long)n * 64 + lane] = acc;
    }
}

// ---------------------------------------------------------------------------
// Kernel 5: out = relu(W @ agg^T)   [128 x 4096]
// ---------------------------------------------------------------------------
__global__ __launch_bounds__(256) void gemm_kernel(
    const float* __restrict__ weight, const float* ws, float* __restrict__ out)
{
    __shared__ __align__(16) float sW[32 * 256];
    __shared__ float sA[32 * 257];
    const int t = threadIdx.x;
    const int nt = blockIdx.x, dt = blockIdx.y;
    const float* agg = ws + OFF_AGG;

    const float4* w4 = (const float4*)(weight + dt * (32 * 256));
    float4* sW4 = (float4*)sW;
    #pragma unroll
    for (int i = 0; i < 8; ++i) sW4[i * 256 + t] = w4[i * 256 + t];

    const float4* a4 = (const float4*)agg + (long)nt * 2048;
    #pragma unroll
    for (int i = 0; i < 8; ++i) {
        int f4i = i * 256 + t;
        float4 v = a4[f4i];
        int row = f4i >> 6, c0 = (f4i & 63) << 2;
        sA[row * 257 + c0 + 0] = v.x;
        sA[row * 257 + c0 + 1] = v.y;
        sA[row * 257 + c0 + 2] = v.z;
        sA[row * 257 + c0 + 3] = v.w;
    }
    __syncthreads();

    const int n = t & 31, g = t >> 5;
    const float* sAn = sA + n * 257;
    const float* sWg = sW + g * (4 * 256);
    float acc[4] = {0.f, 0.f, 0.f, 0.f};
    for (int c4 = 0; c4 < 64; ++c4) {
        float a0 = sAn[c4 * 4 + 0], a1 = sAn[c4 * 4 + 1];
        float a2 = sAn[c4 * 4 + 2], a3 = sAn[c4 * 4 + 3];
        #pragma unroll
        for (int i = 0; i < 4; ++i) {
            const float4 wvv = *(const float4*)(sWg + i * 256 + c4 * 4);
            acc[i] = fmaf(wvv.x, a0, acc[i]);
            acc[i] = fmaf(wvv.y, a1, acc[i]);
            acc[i] = fmaf(wvv.z, a2, acc[i]);
            acc[i] = fmaf(wvv.w, a3, acc[i]);
        }
    }
    float* outp = out + (long)(dt * 32 + g * 4) * 4096 + nt * 32 + n;
    #pragma unroll
    for (int i = 0; i < 4; ++i) outp[(long)i * 4096] = fmaxf(acc[i], 0.f);
}

// ---------------------------------------------------------------------------
extern "C" void kernel_launch(void* const* d_in, const int* in_sizes, int n_in,
                              void* d_out, int out_size, void* d_ws, size_t ws_size,
                              hipStream_t stream)
{
    const float* features = (const float*)d_in[0];
    const float* weight   = (const float*)d_in[1];
    const float* W1       = (const float*)d_in[2];
    const float* b1       = (const float*)d_in[3];
    const float* W2       = (const float*)d_in[4];
    const float* b2       = (const float*)d_in[5];
    const int*   picked   = (const int*)d_in[6];
    const int*   labels   = (const int*)d_in[7];
    const int*   neigh    = (const int*)d_in[8];
    const int*   cnd      = (const int*)d_in[9];
    float* out = (float*)d_out;
    float* ws  = (float*)d_ws;

    dall_kernel<<<dim3(391, 3), 256, 0, stream>>>(features, W1, b1, W2, b2, ws);
    gather_kernel<<<3120, 256, 0, stream>>>(picked, neigh, cnd, ws);
    rho_kernel<<<6, 1024, 0, stream>>>(ws, labels);
    agg_kernel<<<2048, 256, 0, stream>>>(features, picked, neigh, cnd, ws);
    gemm_kernel<<<dim3(128, 4), 256, 0, stream>>>(weight, ws, out);
}

// Round 5
// 440.159 us; speedup vs baseline: 2.2386x; 1.2757x over previous
//
#include <hip/hip_runtime.h>
#include <math.h>

#define NN 50000
#define FD 256
#define DE 128
#define RR 3
#define NP 4096
#define KN 32

// workspace layout (float offsets)
#define OFF_DPICK 0                 // [3][4096]   raw d for picked nodes
#define OFF_DNB   12288             // [3][4096][32]  |d_pick - d_neigh|
#define OFF_DCD   405504            // [3][4096][32]  |d_pick - d_cand|
#define OFF_RHOM  798720            // [3]
#define OFF_RHOP  798724            // [3]
#define OFF_DALL  798976            // [3][50000]  (aliases AGG; dead before agg writes)
#define OFF_AGG   798976            // [4096][256]
// --- rho_minus scratch: lives after DALL end (948976) inside AGG region;
//     written between gather and agg, dead once agg runs. ---
#define OFF_HIST  948976            // int[3][2048]
#define OFF_STATE 955120            // int prefix[3], int remK[3]
#define OFF_PSUM  955128            // double[3][16]  (byte offset % 8 == 0)
#define OFF_PCNT  955224            // int[3][16]

__device__ __forceinline__ int wave_red_int(int v) {
    #pragma unroll
    for (int o = 1; o < 64; o <<= 1) v += __shfl_xor(v, o);
    return v;
}
__device__ __forceinline__ double wave_red_dbl(double v) {
    #pragma unroll
    for (int o = 1; o < 64; o <<= 1) v += __shfl_xor(v, o);
    return v;
}

// exact K-th largest bit pattern of non-negative floats in LDS array arr[0..L)
__device__ unsigned kth_bits(const float* arr, int L, int K,
                             int (*cnt_sh)[16], unsigned* x_sh_p) {
    const int tid = threadIdx.x, lane = tid & 63, wv = tid >> 6;
    unsigned x = 0;
    for (int b = 27; b >= 0; b -= 3) {
        int cnt[7];
        #pragma unroll
        for (int q = 0; q < 7; ++q) cnt[q] = 0;
        for (int i = tid; i < L; i += 1024) {
            unsigned vb = __float_as_uint(arr[i]);
            #pragma unroll
            for (int q = 0; q < 7; ++q) cnt[q] += (vb >= (x | ((unsigned)(q + 1) << b)));
        }
        #pragma unroll
        for (int q = 0; q < 7; ++q) cnt[q] = wave_red_int(cnt[q]);
        if (lane == 0) {
            #pragma unroll
            for (int q = 0; q < 7; ++q) cnt_sh[q][wv] = cnt[q];
        }
        __syncthreads();
        if (tid == 0) {
            unsigned nx = x;
            for (int q = 6; q >= 0; --q) {
                int tot = 0;
                for (int w = 0; w < 16; ++w) tot += cnt_sh[q][w];
                if (tot >= K) { nx = x | ((unsigned)(q + 1) << b); break; }
            }
            *x_sh_p = nx;
        }
        __syncthreads();
        x = *x_sh_p;
        __syncthreads();
    }
    return x;
}

// ---------------------------------------------------------------------------
// Kernel 1: d_all[r][node] for ALL nodes (150K MLP evals).
// ---------------------------------------------------------------------------
__global__ __launch_bounds__(256, 4) void dall_kernel(
    const float* __restrict__ features,
    const float* __restrict__ W1, const float* __restrict__ b1,
    const float* __restrict__ W2, const float* __restrict__ b2,
    float* ws)
{
    const int r = blockIdx.y;
    const int wid = blockIdx.x * 4 + (threadIdx.x >> 6);
    const int lane = threadIdx.x & 63;
    const int s = lane >> 4, j = lane & 15;
    const int base = wid * 32;
    if (base >= NN) return;

    float w1f[64];
    const float* W1r = W1 + r * (FD * 16);
    #pragma unroll
    for (int tt = 0; tt < 64; ++tt) w1f[tt] = W1r[(s * 64 + tt) * 16 + j];
    const float b1v = b1[r * 16 + j];
    const float w2v = W2[(r * 16 + j) * 2 + 1];
    const float b2v = b2[r * 2 + 1];

    float res = 0.f;
    #pragma unroll 2
    for (int i = 0; i < 32; ++i) {
        const int node = min(base + i, NN - 1);
        const float4* x4 = (const float4*)(features + (long)node * FD);
        float acc = 0.f;
        #pragma unroll
        for (int t4 = 0; t4 < 16; ++t4) {
            float4 xv = x4[s * 16 + t4];
            acc = fmaf(xv.x, w1f[4 * t4 + 0], acc);
            acc = fmaf(xv.y, w1f[4 * t4 + 1], acc);
            acc = fmaf(xv.z, w1f[4 * t4 + 2], acc);
            acc = fmaf(xv.w, w1f[4 * t4 + 3], acc);
        }
        acc += __shfl_xor(acc, 16);
        acc += __shfl_xor(acc, 32);
        float h = fmaxf(acc + b1v, 0.f);
        float p = h * w2v;
        p += __shfl_xor(p, 1);
        p += __shfl_xor(p, 2);
        p += __shfl_xor(p, 4);
        p += __shfl_xor(p, 8);
        if (lane == i) res = p;
    }
    const int node = base + lane;
    if (lane < 32 && node < NN)
        ws[OFF_DALL + r * NN + node] = 1.f / (1.f + expf(-(res + b2v)));
}

// ---------------------------------------------------------------------------
// Kernel 2: gather d_pick + |diff| arrays; also init hist/state for rho_minus.
// ---------------------------------------------------------------------------
__global__ __launch_bounds__(256) void gather_kernel(
    const int* __restrict__ picked, const int* __restrict__ neigh,
    const int* __restrict__ cand, float* ws)
{
    const int t = blockIdx.x * 256 + threadIdx.x;
    const float* dall = ws + OFF_DALL;
    if (t < 6144) ((int*)(ws + OFF_HIST))[t] = 0;
    else if (t < 6150) {
        int* st = (int*)(ws + OFF_STATE);
        if (t < 6147) st[t - 6144] = 0;          // prefix
        else          st[t - 6147 + 3] = NP / 2; // remK = 2048
    }
    if (t < RR * NP) {
        const int r = t >> 12;
        ws[OFF_DPICK + t] = dall[r * NN + picked[t]];
    } else if (t < RR * NP + RR * NP * KN) {
        const int off = t - RR * NP;
        const int r = off >> 17;
        const int n = (off >> 5) & (NP - 1);
        const float dp = dall[r * NN + picked[r * NP + n]];
        ws[OFF_DNB + off] = fabsf(dp - dall[r * NN + neigh[off]]);
    } else {
        const int off = t - RR * NP - RR * NP * KN;
        const int r = off >> 17;
        const int n = (off >> 5) & (NP - 1);
        const float dp = dall[r * NN + picked[r * NP + n]];
        ws[OFF_DCD + off] = fabsf(dp - dall[r * NN + cand[off]]);
    }
}

// ---------------------------------------------------------------------------
// rho_minus chain: 3-level radix histogram drill-down (11+11+10 bits), exact.
// ---------------------------------------------------------------------------
__global__ __launch_bounds__(256) void rho_hist_kernel(float* ws, int pass)
{
    __shared__ int h[4][2048];
    const int tid = threadIdx.x, wv = tid >> 6;
    const int r = blockIdx.y;
    for (int i = tid; i < 8192; i += 256) ((int*)h)[i] = 0;
    __syncthreads();

    const int* st = (const int*)(ws + OFF_STATE);
    const unsigned prefix = (unsigned)st[r];
    const float* __restrict__ dnb = ws + OFF_DNB + r * (NP * KN);
    const int base = blockIdx.x * 8192;
    #pragma unroll 4
    for (int k = 0; k < 32; ++k) {
        unsigned vb = __float_as_uint(dnb[base + k * 256 + tid]);
        int bin; bool ok;
        if (pass == 0)      { bin = vb >> 21;           ok = true; }
        else if (pass == 1) { bin = (vb >> 10) & 0x7FF; ok = ((vb >> 21) == prefix); }
        else                { bin = vb & 0x3FF;         ok = ((vb >> 10) == prefix); }
        if (ok) atomicAdd(&h[wv][bin], 1);
    }
    __syncthreads();
    int* hist = (int*)(ws + OFF_HIST) + r * 2048;
    for (int b = tid; b < 2048; b += 256) {
        int s = h[0][b] + h[1][b] + h[2][b] + h[3][b];
        if (s) atomicAdd(&hist[b], s);
    }
}

__global__ __launch_bounds__(1024) void rho_select_kernel(float* ws, int pass)
{
    __shared__ int s0[2048], s1[2048];
    const int tid = threadIdx.x;
    const int r = blockIdx.x;
    int* hist = (int*)(ws + OFF_HIST) + r * 2048;
    int* st = (int*)(ws + OFF_STATE);

    s0[tid] = hist[tid]; s0[tid + 1024] = hist[tid + 1024];
    __syncthreads();
    int* src = s0; int* dst = s1;
    for (int off = 1; off < 2048; off <<= 1) {    // suffix sums, 11 steps
        for (int i = tid; i < 2048; i += 1024) {
            int v = src[i];
            if (i + off < 2048) v += src[i + off];
            dst[i] = v;
        }
        __syncthreads();
        int* tmp = src; src = dst; dst = tmp;
    }
    const int remK = st[3 + r];
    for (int i = tid; i < 2048; i += 1024) {
        const int sfx = src[i];
        const int nxt = (i < 2047) ? src[i + 1] : 0;
        if (sfx >= remK && nxt < remK) {          // unique bin B = i
            const unsigned prefix = (unsigned)st[r];
            st[r] = (pass == 0) ? i
                  : (pass == 1) ? (int)((prefix << 11) | (unsigned)i)
                                : (int)((prefix << 10) | (unsigned)i);
            st[3 + r] = remK - nxt;
        }
        hist[i] = 0;                              // re-zero for next pass
    }
}

__global__ __launch_bounds__(256) void rho_sum_kernel(float* ws)
{
    __shared__ double ds[4];
    __shared__ int    is[4];
    const int tid = threadIdx.x, lane = tid & 63, wv = tid >> 6;
    const int r = blockIdx.y;
    const unsigned x = (unsigned)((const int*)(ws + OFF_STATE))[r];
    const float* __restrict__ dnb = ws + OFF_DNB + r * (NP * KN);
    const int base = blockIdx.x * 8192;
    double s = 0.0; int c = 0;
    #pragma unroll 4
    for (int k = 0; k < 32; ++k) {
        float v = dnb[base + k * 256 + tid];
        if (__float_as_uint(v) > x) { s += (double)v; c += 1; }
    }
    s = wave_red_dbl(s); c = wave_red_int(c);
    if (lane == 0) { ds[wv] = s; is[wv] = c; }
    __syncthreads();
    if (tid == 0) {
        double st = ds[0] + ds[1] + ds[2] + ds[3];
        int ct = is[0] + is[1] + is[2] + is[3];
        ((double*)(ws + OFF_PSUM))[r * 16 + blockIdx.x] = st;
        ((int*)(ws + OFF_PCNT))[r * 16 + blockIdx.x] = ct;
    }
}

// ---------------------------------------------------------------------------
// rho_plus (3 blocks, LDS-resident) + rho_minus finalize.
// ---------------------------------------------------------------------------
__global__ __launch_bounds__(1024) void rho_plus_kernel(float* ws, const int* __restrict__ labels)
{
    __shared__ float cv[2048];
    __shared__ float cnd[2048];
    __shared__ float tvb[64];
    __shared__ int   cnt_sh[7][16];
    __shared__ int   ired[16];
    __shared__ double dred[16];
    __shared__ int   m_sh, npos_sh, cnt2_sh;
    __shared__ unsigned x_sh;

    const int tid = threadIdx.x;
    const int lane = tid & 63, wv = tid >> 6;
    const int r = blockIdx.x;

    if (tid == 0) {     // finalize rho_minus[r] from partials
        const double* psum = (const double*)(ws + OFF_PSUM);
        const int* pcnt = (const int*)(ws + OFF_PCNT);
        double tot = 0; int cg = 0;
        for (int i = 0; i < 16; ++i) { tot += psum[r * 16 + i]; cg += pcnt[r * 16 + i]; }
        const unsigned x = (unsigned)((const int*)(ws + OFF_STATE))[r];
        tot += (double)(NP / 2 - cg) * (double)__uint_as_float(x);
        ws[OFF_RHOM + r] = (float)(tot / (double)(NP / 2));
    }

    const float* dpr = ws + OFF_DPICK + r * NP;
    const int* lab = labels + r * NP;
    int np = 0;
    for (int i = tid; i < NP; i += 1024) np += lab[i];
    np = wave_red_int(np);
    if (lane == 0) ired[wv] = np;
    __syncthreads();
    if (tid == 0) {
        int sacc = 0;
        for (int w = 0; w < 16; ++w) sacc += ired[w];
        npos_sh = sacc; m_sh = 0;
    }
    __syncthreads();
    const int minority = (2 * npos_sh <= NP) ? 1 : 0;
    for (int i = tid; i < NP; i += 1024) {
        bool pred = (lab[i] == minority);
        unsigned long long bal = __ballot(pred);
        int wcnt = __popcll(bal);
        int woff = __popcll(bal & ((1ull << lane) - 1ull));
        int bb = 0;
        if (lane == 0 && wcnt) bb = atomicAdd(&m_sh, wcnt);
        bb = __shfl(bb, 0);
        if (pred) cv[bb + woff] = dpr[i];
    }
    __syncthreads();
    const int m = m_sh;

    if (m >= 64) {
        const unsigned thi = kth_bits(cv, m, 32, cnt_sh, &x_sh);
        if (tid == 0) cnt2_sh = 0;
        __syncthreads();
        for (int i = tid; i < m; i += 1024) {
            bool pred = __float_as_uint(cv[i]) > thi;
            unsigned long long bal = __ballot(pred);
            int wcnt = __popcll(bal);
            int woff = __popcll(bal & ((1ull << lane) - 1ull));
            int bb = 0;
            if (lane == 0 && wcnt) bb = atomicAdd(&cnt2_sh, wcnt);
            bb = __shfl(bb, 0);
            if (pred) tvb[bb + woff] = cv[i];
        }
        __syncthreads();
        if (tid < 32 && tid >= cnt2_sh) tvb[tid] = __uint_as_float(thi);
        __syncthreads();
        const unsigned tlo = kth_bits(cv, m, m - 31, cnt_sh, &x_sh);
        if (tid == 0) cnt2_sh = 0;
        __syncthreads();
        for (int i = tid; i < m; i += 1024) {
            bool pred = __float_as_uint(cv[i]) < tlo;
            unsigned long long bal = __ballot(pred);
            int wcnt = __popcll(bal);
            int woff = __popcll(bal & ((1ull << lane) - 1ull));
            int bb = 0;
            if (lane == 0 && wcnt) bb = atomicAdd(&cnt2_sh, wcnt);
            bb = __shfl(bb, 0);
            if (pred) tvb[32 + bb + woff] = cv[i];
        }
        __syncthreads();
        if (tid < 32 && tid >= cnt2_sh) tvb[32 + tid] = __uint_as_float(tlo);
        __syncthreads();
        cnd[tid] = tvb[tid >> 5] - tvb[32 + (tid & 31)];
        cnd[tid + 1024] = 0.0f;
    } else {
        cnd[tid] = 0.0f; cnd[tid + 1024] = 0.0f;
        __syncthreads();
        int idx = 0;
        for (int a = 0; a + 1 < m; ++a)
            for (int bq = a + 1; bq < m; ++bq) {
                if ((idx & 1023) == tid) cnd[idx] = fabsf(cv[a] - cv[bq]);
                ++idx;
            }
    }
    __syncthreads();
    const unsigned tc = kth_bits(cnd, 2048, 32, cnt_sh, &x_sh);
    double ps = 0.0; int pc = 0;
    {
        float v = cnd[tid];
        if (__float_as_uint(v) > tc) { ps += (double)v; pc += 1; }
        v = cnd[tid + 1024];
        if (__float_as_uint(v) > tc) { ps += (double)v; pc += 1; }
    }
    ps = wave_red_dbl(ps); pc = wave_red_int(pc);
    if (lane == 0) { dred[wv] = ps; ired[wv] = pc; }
    __syncthreads();
    if (tid == 0) {
        double tot = 0; int cg = 0;
        for (int w = 0; w < 16; ++w) { tot += dred[w]; cg += ired[w]; }
        tot += (double)(32 - cg) * (double)__uint_as_float(tc);
        ws[OFF_RHOP + r] = (float)(tot / 32.0);
    }
}

// ---------------------------------------------------------------------------
// Kernel: aggregation. 2 waves per n (center+neigh / cand), LDS combine.
// ---------------------------------------------------------------------------
__global__ __launch_bounds__(256) void agg_kernel(
    const float* __restrict__ features,
    const int* __restrict__ picked, const int* __restrict__ neigh,
    const int* __restrict__ cndi, float* ws)
{
    __shared__ float4 sacc[2][64];
    const int wvid = threadIdx.x >> 6;
    const int half = wvid & 1;
    const int pair = wvid >> 1;
    const int n = __builtin_amdgcn_readfirstlane(blockIdx.x * 2 + pair);
    const int lane = threadIdx.x & 63;
    const float4* f4 = (const float4*)features;

    float4 acc = {0.f, 0.f, 0.f, 0.f};
    if (half == 0) acc = f4[(long)picked[n] * 64 + lane];
    const int* __restrict__ isrc = half ? cndi : neigh;
    const float* dsrc = ws + (half ? OFF_DCD : OFF_DNB);
    #pragma unroll
    for (int r = 0; r < RR; ++r) {
        const float rho = ws[(half ? OFF_RHOP : OFF_RHOM) + r];
        const int base = (r * NP + n) * KN;
        const int   id = isrc[base + (lane & 31)];
        const float dv = dsrc[base + (lane & 31)];
        unsigned long long bal = __ballot(dv < rho);
        const unsigned msk = (unsigned)bal;
        #pragma unroll
        for (int c = 0; c < 4; ++c) {
            float4 v[8];
            #pragma unroll
            for (int q = 0; q < 8; ++q) {
                int node = __shfl(id, c * 8 + q);
                v[q] = f4[(long)node * 64 + lane];
            }
            #pragma unroll
            for (int q = 0; q < 8; ++q) {
                float mfl = ((msk >> (c * 8 + q)) & 1) ? 1.f : 0.f;
                acc.x = fmaf(v[q].x, mfl, acc.x);
                acc.y = fmaf(v[q].y, mfl, acc.y);
                acc.z = fmaf(v[q].z, mfl, acc.z);
                acc.w = fmaf(v[q].w, mfl, acc.w);
            }
        }
    }
    if (half == 1) sacc[pair][lane] = acc;
    __syncthreads();
    if (half == 0) {
        float4 o = sacc[pair][lane];
        acc.x += o.x; acc.y += o.y; acc.z += o.z; acc.w += o.w;
        float4* agg4 = (float4*)(ws + OFF_AGG);
        agg4[(long)n * 64 + lane] = acc;
    }
}

// ---------------------------------------------------------------------------
// Kernel: out = relu(W @ agg^T)   [128 x 4096]
// ---------------------------------------------------------------------------
__global__ __launch_bounds__(256) void gemm_kernel(
    const float* __restrict__ weight, const float* ws, float* __restrict__ out)
{
    __shared__ __align__(16) float sW[32 * 256];
    __shared__ float sA[32 * 257];
    const int t = threadIdx.x;
    const int nt = blockIdx.x, dt = blockIdx.y;
    const float* agg = ws + OFF_AGG;

    const float4* w4 = (const float4*)(weight + dt * (32 * 256));
    float4* sW4 = (float4*)sW;
    #pragma unroll
    for (int i = 0; i < 8; ++i) sW4[i * 256 + t] = w4[i * 256 + t];

    const float4* a4 = (const float4*)agg + (long)nt * 2048;
    #pragma unroll
    for (int i = 0; i < 8; ++i) {
        int f4i = i * 256 + t;
        float4 v = a4[f4i];
        int row = f4i >> 6, c0 = (f4i & 63) << 2;
        sA[row * 257 + c0 + 0] = v.x;
        sA[row * 257 + c0 + 1] = v.y;
        sA[row * 257 + c0 + 2] = v.z;
        sA[row * 257 + c0 + 3] = v.w;
    }
    __syncthreads();

    const int n = t & 31, g = t >> 5;
    const float* sAn = sA + n * 257;
    const float* sWg = sW + g * (4 * 256);
    float acc[4] = {0.f, 0.f, 0.f, 0.f};
    for (int c4 = 0; c4 < 64; ++c4) {
        float a0 = sAn[c4 * 4 + 0], a1 = sAn[c4 * 4 + 1];
        float a2 = sAn[c4 * 4 + 2], a3 = sAn[c4 * 4 + 3];
        #pragma unroll
        for (int i = 0; i < 4; ++i) {
            const float4 wvv = *(const float4*)(sWg + i * 256 + c4 * 4);
            acc[i] = fmaf(wvv.x, a0, acc[i]);
            acc[i] = fmaf(wvv.y, a1, acc[i]);
            acc[i] = fmaf(wvv.z, a2, acc[i]);
            acc[i] = fmaf(wvv.w, a3, acc[i]);
        }
    }
    float* outp = out + (long)(dt * 32 + g * 4) * 4096 + nt * 32 + n;
    #pragma unroll
    for (int i = 0; i < 4; ++i) outp[(long)i * 4096] = fmaxf(acc[i], 0.f);
}

// ---------------------------------------------------------------------------
extern "C" void kernel_launch(void* const* d_in, const int* in_sizes, int n_in,
                              void* d_out, int out_size, void* d_ws, size_t ws_size,
                              hipStream_t stream)
{
    const float* features = (const float*)d_in[0];
    const float* weight   = (const float*)d_in[1];
    const float* W1       = (const float*)d_in[2];
    const float* b1       = (const float*)d_in[3];
    const float* W2       = (const float*)d_in[4];
    const float* b2       = (const float*)d_in[5];
    const int*   picked   = (const int*)d_in[6];
    const int*   labels   = (const int*)d_in[7];
    const int*   neigh    = (const int*)d_in[8];
    const int*   cnd      = (const int*)d_in[9];
    float* out = (float*)d_out;
    float* ws  = (float*)d_ws;

    dall_kernel<<<dim3(391, 3), 256, 0, stream>>>(features, W1, b1, W2, b2, ws);
    gather_kernel<<<3120, 256, 0, stream>>>(picked, neigh, cnd, ws);
    rho_hist_kernel<<<dim3(16, 3), 256, 0, stream>>>(ws, 0);
    rho_select_kernel<<<3, 1024, 0, stream>>>(ws, 0);
    rho_hist_kernel<<<dim3(16, 3), 256, 0, stream>>>(ws, 1);
    rho_select_kernel<<<3, 1024, 0, stream>>>(ws, 1);
    rho_hist_kernel<<<dim3(16, 3), 256, 0, stream>>>(ws, 2);
    rho_select_kernel<<<3, 1024, 0, stream>>>(ws, 2);
    rho_sum_kernel<<<dim3(16, 3), 256, 0, stream>>>(ws);
    rho_plus_kernel<<<3, 1024, 0, stream>>>(ws, labels);
    agg_kernel<<<2048, 256, 0, stream>>>(features, picked, neigh, cnd, ws);
    gemm_kernel<<<dim3(128, 4), 256, 0, stream>>>(weight, ws, out);
}

// Round 7
// 384.803 us; speedup vs baseline: 2.5606x; 1.1439x over previous
//
#include <hip/hip_runtime.h>
#include <hip/hip_fp16.h>
#include <math.h>

#define NN 50000
#define FD 256
#define DE 128
#define RR 3
#define NP 4096
#define KN 32

// workspace layout (float offsets)
#define OFF_DPICK 0                 // [3][4096]   raw d for picked nodes
#define OFF_DNB   12288             // [3][4096][32]  |d_pick - d_neigh|
#define OFF_DCD   405504            // [3][4096][32]  |d_pick - d_cand|
#define OFF_RHOM  798720            // [3]
#define OFF_RHOP  798724            // [3]
#define OFF_DALL  798976            // [3][50000]  (aliases AGG; dead before agg writes)
#define OFF_AGG   798976            // [4096][256] -> ends at 1847552
#define OFF_HIST  948976            // int[3][2048]   (after DALL end, inside AGG, dead before agg)
#define OFF_STATE 955120            // int prefix[3], int remK[3]
#define OFF_F16   1847552           // fp16 features [50000][256] = 25.6 MB (only if ws big enough)
#define WS_NEED_F16 33000000ull

__device__ __forceinline__ int wave_red_int(int v) {
    #pragma unroll
    for (int o = 1; o < 64; o <<= 1) v += __shfl_xor(v, o);
    return v;
}
__device__ __forceinline__ double wave_red_dbl(double v) {
    #pragma unroll
    for (int o = 1; o < 64; o <<= 1) v += __shfl_xor(v, o);
    return v;
}

// exact K-th largest bit pattern of non-negative floats in LDS array arr[0..L)
__device__ unsigned kth_bits(const float* arr, int L, int K,
                             int (*cnt_sh)[16], unsigned* x_sh_p) {
    const int tid = threadIdx.x, lane = tid & 63, wv = tid >> 6;
    unsigned x = 0;
    for (int b = 27; b >= 0; b -= 3) {
        int cnt[7];
        #pragma unroll
        for (int q = 0; q < 7; ++q) cnt[q] = 0;
        for (int i = tid; i < L; i += 1024) {
            unsigned vb = __float_as_uint(arr[i]);
            #pragma unroll
            for (int q = 0; q < 7; ++q) cnt[q] += (vb >= (x | ((unsigned)(q + 1) << b)));
        }
        #pragma unroll
        for (int q = 0; q < 7; ++q) cnt[q] = wave_red_int(cnt[q]);
        if (lane == 0) {
            #pragma unroll
            for (int q = 0; q < 7; ++q) cnt_sh[q][wv] = cnt[q];
        }
        __syncthreads();
        if (tid == 0) {
            unsigned nx = x;
            for (int q = 6; q >= 0; --q) {
                int tot = 0;
                for (int w = 0; w < 16; ++w) tot += cnt_sh[q][w];
                if (tot >= K) { nx = x | ((unsigned)(q + 1) << b); break; }
            }
            *x_sh_p = nx;
        }
        __syncthreads();
        x = *x_sh_p;
        __syncthreads();
    }
    return x;
}

// ---------------------------------------------------------------------------
// Kernel 1: fused d_all. Block = 384 thr (6 waves) stages 32 feature rows in
// LDS ONCE (single pass over features), wave w computes r = w>>1 for 16 rows.
// Segment-padded LDS (stride 68 per 64-float quarter) -> conflict-free reads.
// Also emits fp16 feature copy for agg (if make_f16).
// ---------------------------------------------------------------------------
__global__ __launch_bounds__(384) void dall_kernel(
    const float* __restrict__ features,
    const float* __restrict__ W1, const float* __restrict__ b1,
    const float* __restrict__ W2, const float* __restrict__ b2,
    float* ws, int make_f16)
{
    __shared__ float xs[32 * 272];   // 32 rows x (4 segments x 68)
    const int t = threadIdx.x;
    const int base = blockIdx.x * 32;
    unsigned short* bf = (unsigned short*)(ws + OFF_F16);

    #pragma unroll
    for (int i = 0; i < 6; ++i) {
        const int idx = i * 384 + t;            // 2048 float4s = 32 rows
        if (idx < 2048) {
            const int row = idx >> 6, c4 = idx & 63;
            const int node = base + row;
            const float4 v = ((const float4*)features)[(long)min(node, NN - 1) * 64 + c4];
            *(float4*)&xs[row * 272 + (c4 >> 4) * 68 + (c4 & 15) * 4] = v;
            if (make_f16 && node < NN) {
                ushort4 hv;
                hv.x = __half_as_ushort(__float2half(v.x));
                hv.y = __half_as_ushort(__float2half(v.y));
                hv.z = __half_as_ushort(__float2half(v.z));
                hv.w = __half_as_ushort(__float2half(v.w));
                ((ushort4*)bf)[(long)node * 64 + c4] = hv;
            }
        }
    }
    __syncthreads();

    const int wv = t >> 6, lane = t & 63;
    const int r = wv >> 1, half = wv & 1;
    const int s = lane >> 4, j = lane & 15;

    float w1f[64];
    const float* W1r = W1 + r * (FD * 16);
    #pragma unroll
    for (int tt = 0; tt < 64; ++tt) w1f[tt] = W1r[(s * 64 + tt) * 16 + j];
    const float b1v = b1[r * 16 + j];
    const float w2v = W2[(r * 16 + j) * 2 + 1];
    const float b2v = b2[r * 2 + 1];

    float res = 0.f;
    #pragma unroll 4
    for (int i = 0; i < 16; ++i) {
        const float* xp = &xs[(half * 16 + i) * 272 + s * 68];
        float acc = 0.f;
        #pragma unroll
        for (int t4 = 0; t4 < 16; ++t4) {
            const float4 xv = *(const float4*)(xp + t4 * 4);
            acc = fmaf(xv.x, w1f[4 * t4 + 0], acc);
            acc = fmaf(xv.y, w1f[4 * t4 + 1], acc);
            acc = fmaf(xv.z, w1f[4 * t4 + 2], acc);
            acc = fmaf(xv.w, w1f[4 * t4 + 3], acc);
        }
        acc += __shfl_xor(acc, 16);   // reduce over s
        acc += __shfl_xor(acc, 32);
        float h = fmaxf(acc + b1v, 0.f);
        float p = h * w2v;
        p += __shfl_xor(p, 1);        // reduce over j
        p += __shfl_xor(p, 2);
        p += __shfl_xor(p, 4);
        p += __shfl_xor(p, 8);
        if (lane == i) res = p;       // lanes 0..15 collect their row
    }
    const int node = base + half * 16 + lane;
    if (lane < 16 && node < NN)
        ws[OFF_DALL + r * NN + node] = 1.f / (1.f + expf(-(res + b2v)));
}

// ---------------------------------------------------------------------------
// Kernel 2: gather d_pick + |diff| arrays; init hist/state for rho_minus.
// ---------------------------------------------------------------------------
__global__ __launch_bounds__(256) void gather_kernel(
    const int* __restrict__ picked, const int* __restrict__ neigh,
    const int* __restrict__ cand, float* ws)
{
    const int t = blockIdx.x * 256 + threadIdx.x;
    const float* dall = ws + OFF_DALL;
    if (t < 6144) ((int*)(ws + OFF_HIST))[t] = 0;
    else if (t < 6150) {
        int* st = (int*)(ws + OFF_STATE);
        if (t < 6147) st[t - 6144] = 0;          // prefix
        else          st[t - 6147 + 3] = NP / 2; // remK = 2048
    }
    if (t < RR * NP) {
        const int r = t >> 12;
        ws[OFF_DPICK + t] = dall[r * NN + picked[t]];
    } else if (t < RR * NP + RR * NP * KN) {
        const int off = t - RR * NP;
        const int r = off >> 17;
        const int n = (off >> 5) & (NP - 1);
        const float dp = dall[r * NN + picked[r * NP + n]];
        ws[OFF_DNB + off] = fabsf(dp - dall[r * NN + neigh[off]]);
    } else {
        const int off = t - RR * NP - RR * NP * KN;
        const int r = off >> 17;
        const int n = (off >> 5) & (NP - 1);
        const float dp = dall[r * NN + picked[r * NP + n]];
        ws[OFF_DCD + off] = fabsf(dp - dall[r * NN + cand[off]]);
    }
}

// ---------------------------------------------------------------------------
// rho_minus: 3-level radix histogram drill-down (11+11+10 bits), exact.
// ---------------------------------------------------------------------------
__global__ __launch_bounds__(256) void rho_hist_kernel(float* ws, int pass)
{
    __shared__ int h[4][2048];
    const int tid = threadIdx.x, wv = tid >> 6;
    const int r = blockIdx.y;
    for (int i = tid; i < 8192; i += 256) ((int*)h)[i] = 0;
    __syncthreads();

    const int* st = (const int*)(ws + OFF_STATE);
    const unsigned prefix = (unsigned)st[r];
    const float* __restrict__ dnb = ws + OFF_DNB + r * (NP * KN);
    const int base = blockIdx.x * 8192;
    #pragma unroll 4
    for (int k = 0; k < 32; ++k) {
        unsigned vb = __float_as_uint(dnb[base + k * 256 + tid]);
        int bin; bool ok;
        if (pass == 0)      { bin = vb >> 21;           ok = true; }
        else if (pass == 1) { bin = (vb >> 10) & 0x7FF; ok = ((vb >> 21) == prefix); }
        else                { bin = vb & 0x3FF;         ok = ((vb >> 10) == prefix); }
        if (ok) atomicAdd(&h[wv][bin], 1);
    }
    __syncthreads();
    int* hist = (int*)(ws + OFF_HIST) + r * 2048;
    for (int b = tid; b < 2048; b += 256) {
        int s = h[0][b] + h[1][b] + h[2][b] + h[3][b];
        if (s) atomicAdd(&hist[b], s);
    }
}

__global__ __launch_bounds__(1024) void rho_select_kernel(float* ws, int pass)
{
    __shared__ int s0[2048], s1[2048];
    const int tid = threadIdx.x;
    const int r = blockIdx.x;
    int* hist = (int*)(ws + OFF_HIST) + r * 2048;
    int* st = (int*)(ws + OFF_STATE);

    s0[tid] = hist[tid]; s0[tid + 1024] = hist[tid + 1024];
    __syncthreads();
    int* src = s0; int* dst = s1;
    for (int off = 1; off < 2048; off <<= 1) {    // suffix sums, 11 steps
        for (int i = tid; i < 2048; i += 1024) {
            int v = src[i];
            if (i + off < 2048) v += src[i + off];
            dst[i] = v;
        }
        __syncthreads();
        int* tmp = src; src = dst; dst = tmp;
    }
    const int remK = st[3 + r];
    for (int i = tid; i < 2048; i += 1024) {
        const int sfx = src[i];
        const int nxt = (i < 2047) ? src[i + 1] : 0;
        if (sfx >= remK && nxt < remK) {          // unique bin B = i
            const unsigned prefix = (unsigned)st[r];
            st[r] = (pass == 0) ? i
                  : (pass == 1) ? (int)((prefix << 11) | (unsigned)i)
                                : (int)((prefix << 10) | (unsigned)i);
            st[3 + r] = remK - nxt;
        }
        hist[i] = 0;                              // re-zero for next pass
    }
}

// ---------------------------------------------------------------------------
// rho_plus (3 blocks) + fused rho_minus sum/finalize.
// ---------------------------------------------------------------------------
__global__ __launch_bounds__(1024) void rho_plus_kernel(float* ws, const int* __restrict__ labels)
{
    __shared__ float cv[2048];
    __shared__ float cnd[2048];
    __shared__ float tvb[64];
    __shared__ int   cnt_sh[7][16];
    __shared__ int   ired[16];
    __shared__ double dred[16];
    __shared__ int   m_sh, npos_sh, cnt2_sh;
    __shared__ unsigned x_sh;

    const int tid = threadIdx.x;
    const int lane = tid & 63, wv = tid >> 6;
    const int r = blockIdx.x;

    {   // ---- fused rho_minus sum + finalize ----
        const unsigned x = (unsigned)((const int*)(ws + OFF_STATE))[r];
        const float* __restrict__ dnb = ws + OFF_DNB + r * (NP * KN);
        double ps = 0.0; int pc = 0;
        for (int i = tid; i < NP * KN; i += 1024) {
            float v = dnb[i];
            if (__float_as_uint(v) > x) { ps += (double)v; pc += 1; }
        }
        ps = wave_red_dbl(ps); pc = wave_red_int(pc);
        if (lane == 0) { dred[wv] = ps; ired[wv] = pc; }
        __syncthreads();
        if (tid == 0) {
            double tot = 0; int cg = 0;
            for (int w = 0; w < 16; ++w) { tot += dred[w]; cg += ired[w]; }
            tot += (double)(NP / 2 - cg) * (double)__uint_as_float(x);
            ws[OFF_RHOM + r] = (float)(tot / (double)(NP / 2));
        }
        __syncthreads();
    }

    const float* dpr = ws + OFF_DPICK + r * NP;
    const int* lab = labels + r * NP;
    int np = 0;
    for (int i = tid; i < NP; i += 1024) np += lab[i];
    np = wave_red_int(np);
    if (lane == 0) ired[wv] = np;
    __syncthreads();
    if (tid == 0) {
        int sacc = 0;
        for (int w = 0; w < 16; ++w) sacc += ired[w];
        npos_sh = sacc; m_sh = 0;
    }
    __syncthreads();
    const int minority = (2 * npos_sh <= NP) ? 1 : 0;
    for (int i = tid; i < NP; i += 1024) {
        bool pred = (lab[i] == minority);
        unsigned long long bal = __ballot(pred);
        int wcnt = __popcll(bal);
        int woff = __popcll(bal & ((1ull << lane) - 1ull));
        int bb = 0;
        if (lane == 0 && wcnt) bb = atomicAdd(&m_sh, wcnt);
        bb = __shfl(bb, 0);
        if (pred) cv[bb + woff] = dpr[i];
    }
    __syncthreads();
    const int m = m_sh;

    if (m >= 64) {
        const unsigned thi = kth_bits(cv, m, 32, cnt_sh, &x_sh);
        if (tid == 0) cnt2_sh = 0;
        __syncthreads();
        for (int i = tid; i < m; i += 1024) {
            bool pred = __float_as_uint(cv[i]) > thi;
            unsigned long long bal = __ballot(pred);
            int wcnt = __popcll(bal);
            int woff = __popcll(bal & ((1ull << lane) - 1ull));
            int bb = 0;
            if (lane == 0 && wcnt) bb = atomicAdd(&cnt2_sh, wcnt);
            bb = __shfl(bb, 0);
            if (pred) tvb[bb + woff] = cv[i];
        }
        __syncthreads();
        if (tid < 32 && tid >= cnt2_sh) tvb[tid] = __uint_as_float(thi);
        __syncthreads();
        const unsigned tlo = kth_bits(cv, m, m - 31, cnt_sh, &x_sh);
        if (tid == 0) cnt2_sh = 0;
        __syncthreads();
        for (int i = tid; i < m; i += 1024) {
            bool pred = __float_as_uint(cv[i]) < tlo;
            unsigned long long bal = __ballot(pred);
            int wcnt = __popcll(bal);
            int woff = __popcll(bal & ((1ull << lane) - 1ull));
            int bb = 0;
            if (lane == 0 && wcnt) bb = atomicAdd(&cnt2_sh, wcnt);
            bb = __shfl(bb, 0);
            if (pred) tvb[32 + bb + woff] = cv[i];
        }
        __syncthreads();
        if (tid < 32 && tid >= cnt2_sh) tvb[32 + tid] = __uint_as_float(tlo);
        __syncthreads();
        cnd[tid] = tvb[tid >> 5] - tvb[32 + (tid & 31)];
        cnd[tid + 1024] = 0.0f;
    } else {
        cnd[tid] = 0.0f; cnd[tid + 1024] = 0.0f;
        __syncthreads();
        int idx = 0;
        for (int a = 0; a + 1 < m; ++a)
            for (int bq = a + 1; bq < m; ++bq) {
                if ((idx & 1023) == tid) cnd[idx] = fabsf(cv[a] - cv[bq]);
                ++idx;
            }
    }
    __syncthreads();
    const unsigned tc = kth_bits(cnd, 2048, 32, cnt_sh, &x_sh);
    double ps = 0.0; int pc = 0;
    {
        float v = cnd[tid];
        if (__float_as_uint(v) > tc) { ps += (double)v; pc += 1; }
        v = cnd[tid + 1024];
        if (__float_as_uint(v) > tc) { ps += (double)v; pc += 1; }
    }
    ps = wave_red_dbl(ps); pc = wave_red_int(pc);
    if (lane == 0) { dred[wv] = ps; ired[wv] = pc; }
    __syncthreads();
    if (tid == 0) {
        double tot = 0; int cg = 0;
        for (int w = 0; w < 16; ++w) { tot += dred[w]; cg += ired[w]; }
        tot += (double)(32 - cg) * (double)__uint_as_float(tc);
        ws[OFF_RHOP + r] = (float)(tot / 32.0);
    }
}

// ---------------------------------------------------------------------------
// Aggregation, fp16 feature path (masks & center stay exact f32).
// ---------------------------------------------------------------------------
__global__ __launch_bounds__(256) void agg_kernel_f16(
    const float* __restrict__ features,
    const int* __restrict__ picked, const int* __restrict__ neigh,
    const int* __restrict__ cndi, float* ws)
{
    __shared__ float4 sacc[2][64];
    const int wvid = threadIdx.x >> 6;
    const int half = wvid & 1;
    const int pair = wvid >> 1;
    const int n = __builtin_amdgcn_readfirstlane(blockIdx.x * 2 + pair);
    const int lane = threadIdx.x & 63;
    const float4* f4 = (const float4*)features;
    const ushort4* h4 = (const ushort4*)(ws + OFF_F16);

    float4 acc = {0.f, 0.f, 0.f, 0.f};
    if (half == 0) acc = f4[(long)picked[n] * 64 + lane];   // exact f32 center
    const int* __restrict__ isrc = half ? cndi : neigh;
    const float* dsrc = ws + (half ? OFF_DCD : OFF_DNB);
    #pragma unroll
    for (int r = 0; r < RR; ++r) {
        const float rho = ws[(half ? OFF_RHOP : OFF_RHOM) + r];
        const int base = (r * NP + n) * KN;
        const int   id = isrc[base + (lane & 31)];
        const float dv = dsrc[base + (lane & 31)];
        unsigned long long bal = __ballot(dv < rho);
        const unsigned msk = (unsigned)bal;
        #pragma unroll
        for (int c = 0; c < 2; ++c) {
            ushort4 v[16];
            #pragma unroll
            for (int q = 0; q < 16; ++q) {
                int node = __shfl(id, c * 16 + q);
                v[q] = h4[(long)node * 64 + lane];
            }
            #pragma unroll
            for (int q = 0; q < 16; ++q) {
                float mfl = ((msk >> (c * 16 + q)) & 1) ? 1.f : 0.f;
                acc.x = fmaf(__half2float(__ushort_as_half(v[q].x)), mfl, acc.x);
                acc.y = fmaf(__half2float(__ushort_as_half(v[q].y)), mfl, acc.y);
                acc.z = fmaf(__half2float(__ushort_as_half(v[q].z)), mfl, acc.z);
                acc.w = fmaf(__half2float(__ushort_as_half(v[q].w)), mfl, acc.w);
            }
        }
    }
    if (half == 1) sacc[pair][lane] = acc;
    __syncthreads();
    if (half == 0) {
        float4 o = sacc[pair][lane];
        acc.x += o.x; acc.y += o.y; acc.z += o.z; acc.w += o.w;
        float4* agg4 = (float4*)(ws + OFF_AGG);
        agg4[(long)n * 64 + lane] = acc;
    }
}

// f32 fallback (identical to round 5) — used when ws too small for fp16 copy.
__global__ __launch_bounds__(256) void agg_kernel_f32(
    const float* __restrict__ features,
    const int* __restrict__ picked, const int* __restrict__ neigh,
    const int* __restrict__ cndi, float* ws)
{
    __shared__ float4 sacc[2][64];
    const int wvid = threadIdx.x >> 6;
    const int half = wvid & 1;
    const int pair = wvid >> 1;
    const int n = __builtin_amdgcn_readfirstlane(blockIdx.x * 2 + pair);
    const int lane = threadIdx.x & 63;
    const float4* f4 = (const float4*)features;

    float4 acc = {0.f, 0.f, 0.f, 0.f};
    if (half == 0) acc = f4[(long)picked[n] * 64 + lane];
    const int* __restrict__ isrc = half ? cndi : neigh;
    const float* dsrc = ws + (half ? OFF_DCD : OFF_DNB);
    #pragma unroll
    for (int r = 0; r < RR; ++r) {
        const float rho = ws[(half ? OFF_RHOP : OFF_RHOM) + r];
        const int base = (r * NP + n) * KN;
        const int   id = isrc[base + (lane & 31)];
        const float dv = dsrc[base + (lane & 31)];
        unsigned long long bal = __ballot(dv < rho);
        const unsigned msk = (unsigned)bal;
        #pragma unroll
        for (int c = 0; c < 4; ++c) {
            float4 v[8];
            #pragma unroll
            for (int q = 0; q < 8; ++q) {
                int node = __shfl(id, c * 8 + q);
                v[q] = f4[(long)node * 64 + lane];
            }
            #pragma unroll
            for (int q = 0; q < 8; ++q) {
                float mfl = ((msk >> (c * 8 + q)) & 1) ? 1.f : 0.f;
                acc.x = fmaf(v[q].x, mfl, acc.x);
                acc.y = fmaf(v[q].y, mfl, acc.y);
                acc.z = fmaf(v[q].z, mfl, acc.z);
                acc.w = fmaf(v[q].w, mfl, acc.w);
            }
        }
    }
    if (half == 1) sacc[pair][lane] = acc;
    __syncthreads();
    if (half == 0) {
        float4 o = sacc[pair][lane];
        acc.x += o.x; acc.y += o.y; acc.z += o.z; acc.w += o.w;
        float4* agg4 = (float4*)(ws + OFF_AGG);
        agg4[(long)n * 64 + lane] = acc;
    }
}

// ---------------------------------------------------------------------------
// Kernel: out = relu(W @ agg^T)   [128 x 4096]
// ---------------------------------------------------------------------------
__global__ __launch_bounds__(256) void gemm_kernel(
    const float* __restrict__ weight, const float* ws, float* __restrict__ out)
{
    __shared__ __align__(16) float sW[32 * 256];
    __shared__ float sA[32 * 257];
    const int t = threadIdx.x;
    const int nt = blockIdx.x, dt = blockIdx.y;
    const float* agg = ws + OFF_AGG;

    const float4* w4 = (const float4*)(weight + dt * (32 * 256));
    float4* sW4 = (float4*)sW;
    #pragma unroll
    for (int i = 0; i < 8; ++i) sW4[i * 256 + t] = w4[i * 256 + t];

    const float4* a4 = (const float4*)agg + (long)nt * 2048;
    #pragma unroll
    for (int i = 0; i < 8; ++i) {
        int f4i = i * 256 + t;
        float4 v = a4[f4i];
        int row = f4i >> 6, c0 = (f4i & 63) << 2;
        sA[row * 257 + c0 + 0] = v.x;
        sA[row * 257 + c0 + 1] = v.y;
        sA[row * 257 + c0 + 2] = v.z;
        sA[row * 257 + c0 + 3] = v.w;
    }
    __syncthreads();

    const int n = t & 31, g = t >> 5;
    const float* sAn = sA + n * 257;
    const float* sWg = sW + g * (4 * 256);
    float acc[4] = {0.f, 0.f, 0.f, 0.f};
    for (int c4 = 0; c4 < 64; ++c4) {
        float a0 = sAn[c4 * 4 + 0], a1 = sAn[c4 * 4 + 1];
        float a2 = sAn[c4 * 4 + 2], a3 = sAn[c4 * 4 + 3];
        #pragma unroll
        for (int i = 0; i < 4; ++i) {
            const float4 wvv = *(const float4*)(sWg + i * 256 + c4 * 4);
            acc[i] = fmaf(wvv.x, a0, acc[i]);
            acc[i] = fmaf(wvv.y, a1, acc[i]);
            acc[i] = fmaf(wvv.z, a2, acc[i]);
            acc[i] = fmaf(wvv.w, a3, acc[i]);
        }
    }
    float* outp = out + (long)(dt * 32 + g * 4) * 4096 + nt * 32 + n;
    #pragma unroll
    for (int i = 0; i < 4; ++i) outp[(long)i * 4096] = fmaxf(acc[i], 0.f);
}

// ---------------------------------------------------------------------------
extern "C" void kernel_launch(void* const* d_in, const int* in_sizes, int n_in,
                              void* d_out, int out_size, void* d_ws, size_t ws_size,
                              hipStream_t stream)
{
    const float* features = (const float*)d_in[0];
    const float* weight   = (const float*)d_in[1];
    const float* W1       = (const float*)d_in[2];
    const float* b1       = (const float*)d_in[3];
    const float* W2       = (const float*)d_in[4];
    const float* b2       = (const float*)d_in[5];
    const int*   picked   = (const int*)d_in[6];
    const int*   labels   = (const int*)d_in[7];
    const int*   neigh    = (const int*)d_in[8];
    const int*   cnd      = (const int*)d_in[9];
    float* out = (float*)d_out;
    float* ws  = (float*)d_ws;

    const int use_f16 = (ws_size >= WS_NEED_F16) ? 1 : 0;

    dall_kernel<<<1563, 384, 0, stream>>>(features, W1, b1, W2, b2, ws, use_f16);
    gather_kernel<<<3120, 256, 0, stream>>>(picked, neigh, cnd, ws);
    rho_hist_kernel<<<dim3(16, 3), 256, 0, stream>>>(ws, 0);
    rho_select_kernel<<<3, 1024, 0, stream>>>(ws, 0);
    rho_hist_kernel<<<dim3(16, 3), 256, 0, stream>>>(ws, 1);
    rho_select_kernel<<<3, 1024, 0, stream>>>(ws, 1);
    rho_hist_kernel<<<dim3(16, 3), 256, 0, stream>>>(ws, 2);
    rho_select_kernel<<<3, 1024, 0, stream>>>(ws, 2);
    rho_plus_kernel<<<3, 1024, 0, stream>>>(ws, labels);
    if (use_f16)
        agg_kernel_f16<<<2048, 256, 0, stream>>>(features, picked, neigh, cnd, ws);
    else
        agg_kernel_f32<<<2048, 256, 0, stream>>>(features, picked, neigh, cnd, ws);
    gemm_kernel<<<dim3(128, 4), 256, 0, stream>>>(weight, ws, out);
}

// Round 8
// 381.946 us; speedup vs baseline: 2.5797x; 1.0075x over previous
//
#include <hip/hip_runtime.h>
#include <hip/hip_fp16.h>
#include <math.h>

#define NN 50000
#define FD 256
#define DE 128
#define RR 3
#define NP 4096
#define KN 32

// workspace layout (float offsets)
#define OFF_DPICK 0                 // [3][4096]   raw d for picked nodes
#define OFF_DNB   12288             // [3][4096][32]  |d_pick - d_neigh|
#define OFF_DCD   405504            // [3][4096][32]  |d_pick - d_cand|
#define OFF_RHOM  798720            // [3]
#define OFF_RHOP  798724            // [3]
#define OFF_DALL  798976            // [3][50000]  (aliases AGG; dead before agg writes)
#define OFF_AGG   798976            // [4096][256] -> ends at 1847552
#define OFF_HIST  948976            // int[3][2048]   (after DALL end, inside AGG, dead before agg)
#define OFF_STATE 955120            // int prefix[3], int remK[3]
#define OFF_F16   1847552           // fp16 features [50000][256] = 25.6 MB (only if ws big enough)
#define WS_NEED_F16 33000000ull

__device__ __forceinline__ int wave_red_int(int v) {
    #pragma unroll
    for (int o = 1; o < 64; o <<= 1) v += __shfl_xor(v, o);
    return v;
}
__device__ __forceinline__ double wave_red_dbl(double v) {
    #pragma unroll
    for (int o = 1; o < 64; o <<= 1) v += __shfl_xor(v, o);
    return v;
}

// exact K-th largest bit pattern of non-negative floats in LDS array arr[0..L).
// Fully parallel digit select: wave 0 cross-reduces the per-wave counts in
// registers (no serial tid0 loop); all threads then derive the digit
// identically from tot[]. 2 barriers per pass, 10 passes.
__device__ unsigned kth_bits(const float* arr, int L, int K,
                             int* cw /*[128]*/, int* tot /*[8]*/) {
    const int tid = threadIdx.x, lane = tid & 63, wv = tid >> 6;
    unsigned x = 0;
    for (int b = 27; b >= 0; b -= 3) {
        int cnt[7];
        #pragma unroll
        for (int q = 0; q < 7; ++q) cnt[q] = 0;
        for (int i = tid; i < L; i += 1024) {
            unsigned vb = __float_as_uint(arr[i]);
            #pragma unroll
            for (int q = 0; q < 7; ++q) cnt[q] += (vb >= (x | ((unsigned)(q + 1) << b)));
        }
        #pragma unroll
        for (int q = 0; q < 7; ++q) cnt[q] = wave_red_int(cnt[q]);
        if (lane == 0) {
            #pragma unroll
            for (int q = 0; q < 7; ++q) cw[wv * 8 + q] = cnt[q];
        }
        __syncthreads();
        if (wv == 0) {                       // parallel 16-wave reduce, in-register
            const int q = lane >> 3, sub = lane & 7;
            int v = (q < 7) ? (cw[sub * 8 + q] + cw[(sub + 8) * 8 + q]) : 0;
            v += __shfl_xor(v, 1);
            v += __shfl_xor(v, 2);
            v += __shfl_xor(v, 4);
            if (sub == 0 && q < 7) tot[q] = v;
        }
        __syncthreads();
        unsigned nx = x;
        #pragma unroll
        for (int q = 6; q >= 0; --q) {
            if (tot[q] >= K) { nx = x | ((unsigned)(q + 1) << b); break; }
        }
        x = nx;                              // identical in all threads
    }
    return x;
}

// ---------------------------------------------------------------------------
// Kernel 1: fused d_all. Block = 384 thr (6 waves) stages 32 feature rows in
// LDS ONCE (single pass over features), wave w computes r = w>>1 for 16 rows.
// Also emits fp16 feature copy for agg (if make_f16).
// ---------------------------------------------------------------------------
__global__ __launch_bounds__(384) void dall_kernel(
    const float* __restrict__ features,
    const float* __restrict__ W1, const float* __restrict__ b1,
    const float* __restrict__ W2, const float* __restrict__ b2,
    float* ws, int make_f16)
{
    __shared__ float xs[32 * 272];   // 32 rows x (4 segments x 68)
    const int t = threadIdx.x;
    const int base = blockIdx.x * 32;
    unsigned short* bf = (unsigned short*)(ws + OFF_F16);

    #pragma unroll
    for (int i = 0; i < 6; ++i) {
        const int idx = i * 384 + t;            // 2048 float4s = 32 rows
        if (idx < 2048) {
            const int row = idx >> 6, c4 = idx & 63;
            const int node = base + row;
            const float4 v = ((const float4*)features)[(long)min(node, NN - 1) * 64 + c4];
            *(float4*)&xs[row * 272 + (c4 >> 4) * 68 + (c4 & 15) * 4] = v;
            if (make_f16 && node < NN) {
                ushort4 hv;
                hv.x = __half_as_ushort(__float2half(v.x));
                hv.y = __half_as_ushort(__float2half(v.y));
                hv.z = __half_as_ushort(__float2half(v.z));
                hv.w = __half_as_ushort(__float2half(v.w));
                ((ushort4*)bf)[(long)node * 64 + c4] = hv;
            }
        }
    }
    __syncthreads();

    const int wv = t >> 6, lane = t & 63;
    const int r = wv >> 1, half = wv & 1;
    const int s = lane >> 4, j = lane & 15;

    float w1f[64];
    const float* W1r = W1 + r * (FD * 16);
    #pragma unroll
    for (int tt = 0; tt < 64; ++tt) w1f[tt] = W1r[(s * 64 + tt) * 16 + j];
    const float b1v = b1[r * 16 + j];
    const float w2v = W2[(r * 16 + j) * 2 + 1];
    const float b2v = b2[r * 2 + 1];

    float res = 0.f;
    #pragma unroll 4
    for (int i = 0; i < 16; ++i) {
        const float* xp = &xs[(half * 16 + i) * 272 + s * 68];
        float acc = 0.f;
        #pragma unroll
        for (int t4 = 0; t4 < 16; ++t4) {
            const float4 xv = *(const float4*)(xp + t4 * 4);
            acc = fmaf(xv.x, w1f[4 * t4 + 0], acc);
            acc = fmaf(xv.y, w1f[4 * t4 + 1], acc);
            acc = fmaf(xv.z, w1f[4 * t4 + 2], acc);
            acc = fmaf(xv.w, w1f[4 * t4 + 3], acc);
        }
        acc += __shfl_xor(acc, 16);   // reduce over s
        acc += __shfl_xor(acc, 32);
        float h = fmaxf(acc + b1v, 0.f);
        float p = h * w2v;
        p += __shfl_xor(p, 1);        // reduce over j
        p += __shfl_xor(p, 2);
        p += __shfl_xor(p, 4);
        p += __shfl_xor(p, 8);
        if (lane == i) res = p;       // lanes 0..15 collect their row
    }
    const int node = base + half * 16 + lane;
    if (lane < 16 && node < NN)
        ws[OFF_DALL + r * NN + node] = 1.f / (1.f + expf(-(res + b2v)));
}

// ---------------------------------------------------------------------------
// Kernel 2: gather d_pick + |diff| arrays; init hist/state for rho_minus.
// ---------------------------------------------------------------------------
__global__ __launch_bounds__(256) void gather_kernel(
    const int* __restrict__ picked, const int* __restrict__ neigh,
    const int* __restrict__ cand, float* ws)
{
    const int t = blockIdx.x * 256 + threadIdx.x;
    const float* dall = ws + OFF_DALL;
    if (t < 6144) ((int*)(ws + OFF_HIST))[t] = 0;
    else if (t < 6150) {
        int* st = (int*)(ws + OFF_STATE);
        if (t < 6147) st[t - 6144] = 0;          // prefix
        else          st[t - 6147 + 3] = NP / 2; // remK = 2048
    }
    if (t < RR * NP) {
        const int r = t >> 12;
        ws[OFF_DPICK + t] = dall[r * NN + picked[t]];
    } else if (t < RR * NP + RR * NP * KN) {
        const int off = t - RR * NP;
        const int r = off >> 17;
        const int n = (off >> 5) & (NP - 1);
        const float dp = dall[r * NN + picked[r * NP + n]];
        ws[OFF_DNB + off] = fabsf(dp - dall[r * NN + neigh[off]]);
    } else {
        const int off = t - RR * NP - RR * NP * KN;
        const int r = off >> 17;
        const int n = (off >> 5) & (NP - 1);
        const float dp = dall[r * NN + picked[r * NP + n]];
        ws[OFF_DCD + off] = fabsf(dp - dall[r * NN + cand[off]]);
    }
}

// ---------------------------------------------------------------------------
// rho_minus: 3-level radix histogram drill-down (11+11+10 bits), exact.
// ---------------------------------------------------------------------------
__global__ __launch_bounds__(256) void rho_hist_kernel(float* ws, int pass)
{
    __shared__ int h[4][2048];
    const int tid = threadIdx.x, wv = tid >> 6;
    const int r = blockIdx.y;
    for (int i = tid; i < 8192; i += 256) ((int*)h)[i] = 0;
    __syncthreads();

    const int* st = (const int*)(ws + OFF_STATE);
    const unsigned prefix = (unsigned)st[r];
    const float* __restrict__ dnb = ws + OFF_DNB + r * (NP * KN);
    const int base = blockIdx.x * 8192;
    #pragma unroll 4
    for (int k = 0; k < 32; ++k) {
        unsigned vb = __float_as_uint(dnb[base + k * 256 + tid]);
        int bin; bool ok;
        if (pass == 0)      { bin = vb >> 21;           ok = true; }
        else if (pass == 1) { bin = (vb >> 10) & 0x7FF; ok = ((vb >> 21) == prefix); }
        else                { bin = vb & 0x3FF;         ok = ((vb >> 10) == prefix); }
        if (ok) atomicAdd(&h[wv][bin], 1);
    }
    __syncthreads();
    int* hist = (int*)(ws + OFF_HIST) + r * 2048;
    for (int b = tid; b < 2048; b += 256) {
        int s = h[0][b] + h[1][b] + h[2][b] + h[3][b];
        if (s) atomicAdd(&hist[b], s);
    }
}

__global__ __launch_bounds__(1024) void rho_select_kernel(float* ws, int pass)
{
    __shared__ int s0[2048], s1[2048];
    const int tid = threadIdx.x;
    const int r = blockIdx.x;
    int* hist = (int*)(ws + OFF_HIST) + r * 2048;
    int* st = (int*)(ws + OFF_STATE);

    s0[tid] = hist[tid]; s0[tid + 1024] = hist[tid + 1024];
    __syncthreads();
    int* src = s0; int* dst = s1;
    for (int off = 1; off < 2048; off <<= 1) {    // suffix sums, 11 steps
        for (int i = tid; i < 2048; i += 1024) {
            int v = src[i];
            if (i + off < 2048) v += src[i + off];
            dst[i] = v;
        }
        __syncthreads();
        int* tmp = src; src = dst; dst = tmp;
    }
    const int remK = st[3 + r];
    for (int i = tid; i < 2048; i += 1024) {
        const int sfx = src[i];
        const int nxt = (i < 2047) ? src[i + 1] : 0;
        if (sfx >= remK && nxt < remK) {          // unique bin B = i
            const unsigned prefix = (unsigned)st[r];
            st[r] = (pass == 0) ? i
                  : (pass == 1) ? (int)((prefix << 11) | (unsigned)i)
                                : (int)((prefix << 10) | (unsigned)i);
            st[3 + r] = remK - nxt;
        }
        hist[i] = 0;                              // re-zero for next pass
    }
}

// ---------------------------------------------------------------------------
// rho_plus (3 blocks) + fused rho_minus sum/finalize.
// ---------------------------------------------------------------------------
__global__ __launch_bounds__(1024) void rho_plus_kernel(float* ws, const int* __restrict__ labels)
{
    __shared__ float cv[2048];
    __shared__ float cnd[2048];
    __shared__ float tvb[64];
    __shared__ int   cw[128];       // per-wave digit counts [16][8]
    __shared__ int   tot[8];        // cross-wave totals
    __shared__ int   ired[16];
    __shared__ double dred[16];
    __shared__ int   m_sh, npos_sh, cnt2_sh;

    const int tid = threadIdx.x;
    const int lane = tid & 63, wv = tid >> 6;
    const int r = blockIdx.x;

    {   // ---- fused rho_minus sum + finalize ----
        const unsigned x = (unsigned)((const int*)(ws + OFF_STATE))[r];
        const float* __restrict__ dnb = ws + OFF_DNB + r * (NP * KN);
        double ps = 0.0; int pc = 0;
        for (int i = tid; i < NP * KN; i += 1024) {
            float v = dnb[i];
            if (__float_as_uint(v) > x) { ps += (double)v; pc += 1; }
        }
        ps = wave_red_dbl(ps); pc = wave_red_int(pc);
        if (lane == 0) { dred[wv] = ps; ired[wv] = pc; }
        __syncthreads();
        if (tid == 0) {
            double tot2 = 0; int cg = 0;
            for (int w = 0; w < 16; ++w) { tot2 += dred[w]; cg += ired[w]; }
            tot2 += (double)(NP / 2 - cg) * (double)__uint_as_float(x);
            ws[OFF_RHOM + r] = (float)(tot2 / (double)(NP / 2));
        }
        __syncthreads();
    }

    const float* dpr = ws + OFF_DPICK + r * NP;
    const int* lab = labels + r * NP;
    int np = 0;
    for (int i = tid; i < NP; i += 1024) np += lab[i];
    np = wave_red_int(np);
    if (lane == 0) ired[wv] = np;
    __syncthreads();
    if (tid == 0) {
        int sacc = 0;
        for (int w = 0; w < 16; ++w) sacc += ired[w];
        npos_sh = sacc; m_sh = 0;
    }
    __syncthreads();
    const int minority = (2 * npos_sh <= NP) ? 1 : 0;
    for (int i = tid; i < NP; i += 1024) {
        bool pred = (lab[i] == minority);
        unsigned long long bal = __ballot(pred);
        int wcnt = __popcll(bal);
        int woff = __popcll(bal & ((1ull << lane) - 1ull));
        int bb = 0;
        if (lane == 0 && wcnt) bb = atomicAdd(&m_sh, wcnt);
        bb = __shfl(bb, 0);
        if (pred) cv[bb + woff] = dpr[i];
    }
    __syncthreads();
    const int m = m_sh;

    if (m >= 64) {
        const unsigned thi = kth_bits(cv, m, 32, cw, tot);
        if (tid == 0) cnt2_sh = 0;
        __syncthreads();
        for (int i = tid; i < m; i += 1024) {
            bool pred = __float_as_uint(cv[i]) > thi;
            unsigned long long bal = __ballot(pred);
            int wcnt = __popcll(bal);
            int woff = __popcll(bal & ((1ull << lane) - 1ull));
            int bb = 0;
            if (lane == 0 && wcnt) bb = atomicAdd(&cnt2_sh, wcnt);
            bb = __shfl(bb, 0);
            if (pred) tvb[bb + woff] = cv[i];
        }
        __syncthreads();
        if (tid < 32 && tid >= cnt2_sh) tvb[tid] = __uint_as_float(thi);
        __syncthreads();
        const unsigned tlo = kth_bits(cv, m, m - 31, cw, tot);
        if (tid == 0) cnt2_sh = 0;
        __syncthreads();
        for (int i = tid; i < m; i += 1024) {
            bool pred = __float_as_uint(cv[i]) < tlo;
            unsigned long long bal = __ballot(pred);
            int wcnt = __popcll(bal);
            int woff = __popcll(bal & ((1ull << lane) - 1ull));
            int bb = 0;
            if (lane == 0 && wcnt) bb = atomicAdd(&cnt2_sh, wcnt);
            bb = __shfl(bb, 0);
            if (pred) tvb[32 + bb + woff] = cv[i];
        }
        __syncthreads();
        if (tid < 32 && tid >= cnt2_sh) tvb[32 + tid] = __uint_as_float(tlo);
        __syncthreads();
        cnd[tid] = tvb[tid >> 5] - tvb[32 + (tid & 31)];
        cnd[tid + 1024] = 0.0f;
    } else {
        cnd[tid] = 0.0f; cnd[tid + 1024] = 0.0f;
        __syncthreads();
        int idx = 0;
        for (int a = 0; a + 1 < m; ++a)
            for (int bq = a + 1; bq < m; ++bq) {
                if ((idx & 1023) == tid) cnd[idx] = fabsf(cv[a] - cv[bq]);
                ++idx;
            }
    }
    __syncthreads();
    const unsigned tc = kth_bits(cnd, 2048, 32, cw, tot);
    double ps = 0.0; int pc = 0;
    {
        float v = cnd[tid];
        if (__float_as_uint(v) > tc) { ps += (double)v; pc += 1; }
        v = cnd[tid + 1024];
        if (__float_as_uint(v) > tc) { ps += (double)v; pc += 1; }
    }
    ps = wave_red_dbl(ps); pc = wave_red_int(pc);
    if (lane == 0) { dred[wv] = ps; ired[wv] = pc; }
    __syncthreads();
    if (tid == 0) {
        double tot2 = 0; int cg = 0;
        for (int w = 0; w < 16; ++w) { tot2 += dred[w]; cg += ired[w]; }
        tot2 += (double)(32 - cg) * (double)__uint_as_float(tc);
        ws[OFF_RHOP + r] = (float)(tot2 / 32.0);
    }
}

// ---------------------------------------------------------------------------
// Aggregation, fp16 feature path (masks & center stay exact f32).
// ---------------------------------------------------------------------------
__global__ __launch_bounds__(256) void agg_kernel_f16(
    const float* __restrict__ features,
    const int* __restrict__ picked, const int* __restrict__ neigh,
    const int* __restrict__ cndi, float* ws)
{
    __shared__ float4 sacc[2][64];
    const int wvid = threadIdx.x >> 6;
    const int half = wvid & 1;
    const int pair = wvid >> 1;
    const int n = __builtin_amdgcn_readfirstlane(blockIdx.x * 2 + pair);
    const int lane = threadIdx.x & 63;
    const float4* f4 = (const float4*)features;
    const ushort4* h4 = (const ushort4*)(ws + OFF_F16);

    float4 acc = {0.f, 0.f, 0.f, 0.f};
    if (half == 0) acc = f4[(long)picked[n] * 64 + lane];   // exact f32 center
    const int* __restrict__ isrc = half ? cndi : neigh;
    const float* dsrc = ws + (half ? OFF_DCD : OFF_DNB);
    #pragma unroll
    for (int r = 0; r < RR; ++r) {
        const float rho = ws[(half ? OFF_RHOP : OFF_RHOM) + r];
        const int base = (r * NP + n) * KN;
        const int   id = isrc[base + (lane & 31)];
        const float dv = dsrc[base + (lane & 31)];
        unsigned long long bal = __ballot(dv < rho);
        const unsigned msk = (unsigned)bal;
        #pragma unroll
        for (int c = 0; c < 2; ++c) {
            ushort4 v[16];
            #pragma unroll
            for (int q = 0; q < 16; ++q) {
                int node = __shfl(id, c * 16 + q);
                v[q] = h4[(long)node * 64 + lane];
            }
            #pragma unroll
            for (int q = 0; q < 16; ++q) {
                float mfl = ((msk >> (c * 16 + q)) & 1) ? 1.f : 0.f;
                acc.x = fmaf(__half2float(__ushort_as_half(v[q].x)), mfl, acc.x);
                acc.y = fmaf(__half2float(__ushort_as_half(v[q].y)), mfl, acc.y);
                acc.z = fmaf(__half2float(__ushort_as_half(v[q].z)), mfl, acc.z);
                acc.w = fmaf(__half2float(__ushort_as_half(v[q].w)), mfl, acc.w);
            }
        }
    }
    if (half == 1) sacc[pair][lane] = acc;
    __syncthreads();
    if (half == 0) {
        float4 o = sacc[pair][lane];
        acc.x += o.x; acc.y += o.y; acc.z += o.z; acc.w += o.w;
        float4* agg4 = (float4*)(ws + OFF_AGG);
        agg4[(long)n * 64 + lane] = acc;
    }
}

// f32 fallback — used when ws too small for fp16 copy.
__global__ __launch_bounds__(256) void agg_kernel_f32(
    const float* __restrict__ features,
    const int* __restrict__ picked, const int* __restrict__ neigh,
    const int* __restrict__ cndi, float* ws)
{
    __shared__ float4 sacc[2][64];
    const int wvid = threadIdx.x >> 6;
    const int half = wvid & 1;
    const int pair = wvid >> 1;
    const int n = __builtin_amdgcn_readfirstlane(blockIdx.x * 2 + pair);
    const int lane = threadIdx.x & 63;
    const float4* f4 = (const float4*)features;

    float4 acc = {0.f, 0.f, 0.f, 0.f};
    if (half == 0) acc = f4[(long)picked[n] * 64 + lane];
    const int* __restrict__ isrc = half ? cndi : neigh;
    const float* dsrc = ws + (half ? OFF_DCD : OFF_DNB);
    #pragma unroll
    for (int r = 0; r < RR; ++r) {
        const float rho = ws[(half ? OFF_RHOP : OFF_RHOM) + r];
        const int base = (r * NP + n) * KN;
        const int   id = isrc[base + (lane & 31)];
        const float dv = dsrc[base + (lane & 31)];
        unsigned long long bal = __ballot(dv < rho);
        const unsigned msk = (unsigned)bal;
        #pragma unroll
        for (int c = 0; c < 4; ++c) {
            float4 v[8];
            #pragma unroll
            for (int q = 0; q < 8; ++q) {
                int node = __shfl(id, c * 8 + q);
                v[q] = f4[(long)node * 64 + lane];
            }
            #pragma unroll
            for (int q = 0; q < 8; ++q) {
                float mfl = ((msk >> (c * 8 + q)) & 1) ? 1.f : 0.f;
                acc.x = fmaf(v[q].x, mfl, acc.x);
                acc.y = fmaf(v[q].y, mfl, acc.y);
                acc.z = fmaf(v[q].z, mfl, acc.z);
                acc.w = fmaf(v[q].w, mfl, acc.w);
            }
        }
    }
    if (half == 1) sacc[pair][lane] = acc;
    __syncthreads();
    if (half == 0) {
        float4 o = sacc[pair][lane];
        acc.x += o.x; acc.y += o.y; acc.z += o.z; acc.w += o.w;
        float4* agg4 = (float4*)(ws + OFF_AGG);
        agg4[(long)n * 64 + lane] = acc;
    }
}

// ---------------------------------------------------------------------------
// Kernel: out = relu(W @ agg^T)   [128 x 4096]
// ---------------------------------------------------------------------------
__global__ __launch_bounds__(256) void gemm_kernel(
    const float* __restrict__ weight, const float* ws, float* __restrict__ out)
{
    __shared__ __align__(16) float sW[32 * 256];
    __shared__ float sA[32 * 257];
    const int t = threadIdx.x;
    const int nt = blockIdx.x, dt = blockIdx.y;
    const float* agg = ws + OFF_AGG;

    const float4* w4 = (const float4*)(weight + dt * (32 * 256));
    float4* sW4 = (float4*)sW;
    #pragma unroll
    for (int i = 0; i < 8; ++i) sW4[i * 256 + t] = w4[i * 256 + t];

    const float4* a4 = (const float4*)agg + (long)nt * 2048;
    #pragma unroll
    for (int i = 0; i < 8; ++i) {
        int f4i = i * 256 + t;
        float4 v = a4[f4i];
        int row = f4i >> 6, c0 = (f4i & 63) << 2;
        sA[row * 257 + c0 + 0] = v.x;
        sA[row * 257 + c0 + 1] = v.y;
        sA[row * 257 + c0 + 2] = v.z;
        sA[row * 257 + c0 + 3] = v.w;
    }
    __syncthreads();

    const int n = t & 31, g = t >> 5;
    const float* sAn = sA + n * 257;
    const float* sWg = sW + g * (4 * 256);
    float acc[4] = {0.f, 0.f, 0.f, 0.f};
    for (int c4 = 0; c4 < 64; ++c4) {
        float a0 = sAn[c4 * 4 + 0], a1 = sAn[c4 * 4 + 1];
        float a2 = sAn[c4 * 4 + 2], a3 = sAn[c4 * 4 + 3];
        #pragma unroll
        for (int i = 0; i < 4; ++i) {
            const float4 wvv = *(const float4*)(sWg + i * 256 + c4 * 4);
            acc[i] = fmaf(wvv.x, a0, acc[i]);
            acc[i] = fmaf(wvv.y, a1, acc[i]);
            acc[i] = fmaf(wvv.z, a2, acc[i]);
            acc[i] = fmaf(wvv.w, a3, acc[i]);
        }
    }
    float* outp = out + (long)(dt * 32 + g * 4) * 4096 + nt * 32 + n;
    #pragma unroll
    for (int i = 0; i < 4; ++i) outp[(long)i * 4096] = fmaxf(acc[i], 0.f);
}

// ---------------------------------------------------------------------------
extern "C" void kernel_launch(void* const* d_in, const int* in_sizes, int n_in,
                              void* d_out, int out_size, void* d_ws, size_t ws_size,
                              hipStream_t stream)
{
    const float* features = (const float*)d_in[0];
    const float* weight   = (const float*)d_in[1];
    const float* W1       = (const float*)d_in[2];
    const float* b1       = (const float*)d_in[3];
    const float* W2       = (const float*)d_in[4];
    const float* b2       = (const float*)d_in[5];
    const int*   picked   = (const int*)d_in[6];
    const int*   labels   = (const int*)d_in[7];
    const int*   neigh    = (const int*)d_in[8];
    const int*   cnd      = (const int*)d_in[9];
    float* out = (float*)d_out;
    float* ws  = (float*)d_ws;

    const int use_f16 = (ws_size >= WS_NEED_F16) ? 1 : 0;

    dall_kernel<<<1563, 384, 0, stream>>>(features, W1, b1, W2, b2, ws, use_f16);
    gather_kernel<<<3120, 256, 0, stream>>>(picked, neigh, cnd, ws);
    rho_hist_kernel<<<dim3(16, 3), 256, 0, stream>>>(ws, 0);
    rho_select_kernel<<<3, 1024, 0, stream>>>(ws, 0);
    rho_hist_kernel<<<dim3(16, 3), 256, 0, stream>>>(ws, 1);
    rho_select_kernel<<<3, 1024, 0, stream>>>(ws, 1);
    rho_hist_kernel<<<dim3(16, 3), 256, 0, stream>>>(ws, 2);
    rho_select_kernel<<<3, 1024, 0, stream>>>(ws, 2);
    rho_plus_kernel<<<3, 1024, 0, stream>>>(ws, labels);
    if (use_f16)
        agg_kernel_f16<<<2048, 256, 0, stream>>>(features, picked, neigh, cnd, ws);
    else
        agg_kernel_f32<<<2048, 256, 0, stream>>>(features, picked, neigh, cnd, ws);
    gemm_kernel<<<dim3(128, 4), 256, 0, stream>>>(weight, ws, out);
}